// Round 1
// baseline (4906.957 us; speedup 1.0000x reference)
//
#include <hip/hip_runtime.h>
#include <hip/hip_bf16.h>
#include <math.h>

#define Hn 256
#define Wn 256
#define Cn 64
#define Mk 12
#define NM 24
#define FCH 128
#define HW 65536

__device__ __forceinline__ float gelu_exact(float x) {
    return 0.5f * x * (1.0f + erff(x * 0.7071067811865476f));
}
__device__ __forceinline__ unsigned short f2bf(float f) {
    __hip_bfloat16 h = __float2bfloat16(f);
    return __builtin_bit_cast(unsigned short, h);
}
__device__ __forceinline__ float bfbits(unsigned int x) {
    return __builtin_bit_cast(float, x);
}

// ---------------- tables ----------------
// tc/ts: cos/sin(i*step); twc/tws: [w][k] (legacy, used by k_dftw_x)
// tcs: packed (c,s) float2[256]; tw2: packed (c,s) keyed [k][w] float2[12*256]
__global__ __launch_bounds__(256) void k_init_tables(float* tc, float* ts,
                                                     float* twc, float* tws,
                                                     float* tcs, float* tw2) {
    int i = threadIdx.x;  // 0..255
    const float step = 0.024543692606170259f;  // 2*pi/256
    float c = cosf(i * step), s = sinf(i * step);
    tc[i] = c; ts[i] = s;
    tcs[2 * i] = c; tcs[2 * i + 1] = s;
    for (int k = 0; k < Mk; ++k) {
        int idx = (i * k) & 255;
        float ck = cosf(idx * step), sk = sinf(idx * step);
        twc[i * Mk + k] = ck;
        tws[i * Mk + k] = sk;
        tw2[(k * 256 + i) * 2]     = ck;
        tw2[(k * 256 + i) * 2 + 1] = sk;
    }
}

// ------- spectral weight transpose: scw[l,j,i,o,kx,ky,2] -> scwT[l,j,kx,ky,i,o,2]
// float4 reads (2 complex = ky, ky+1 for one (i,o)) -> 2 scattered float2 writes
__global__ __launch_bounds__(256) void k_prep_w(const float* __restrict__ scw,
                                                float* __restrict__ scwT) {
    int t = blockIdx.x * 256 + threadIdx.x;  // < 2,359,296
    int o  = t & 63;
    int i  = (t >> 6) & 63;
    int r  = t >> 12;           // lj*72 + kx*6 + u, r < 576
    int u  = r % 6;
    int kx = (r / 6) % 12;
    int lj = r / 72;            // 0..7
    int ky = 2 * u;
    size_t in_idx = ((((size_t)lj * 64 + i) * 64 + o) * 144) + kx * Mk + ky;  // even
    float4 v = *(const float4*)(scw + 2 * in_idx);
    size_t o0 = ((((size_t)(lj * 12 + kx) * Mk + ky) * 64 + i) * 64 + o);
    size_t o1 = ((((size_t)(lj * 12 + kx) * Mk + ky + 1) * 64 + i) * 64 + o);
    *(float2*)(scwT + 2 * o0) = make_float2(v.x, v.y);
    *(float2*)(scwT + 2 * o1) = make_float2(v.z, v.w);
}

// ------- DFT along W of x (all 16 batches, 4096 rows), lane-per-row -------
__global__ __launch_bounds__(64) void k_dftw_x(const float* __restrict__ x,
                                               float* __restrict__ Xxw,
                                               const float* __restrict__ twc,
                                               const float* __restrict__ tws) {
    int r = blockIdx.x * 64 + threadIdx.x;  // 0..4095
    const float* hp = x + (size_t)r * Wn;
    float xr[Mk], xi[Mk];
#pragma unroll
    for (int k = 0; k < Mk; ++k) { xr[k] = 0.f; xi[k] = 0.f; }
    for (int w4 = 0; w4 < 64; ++w4) {
        float4 v = ((const float4*)hp)[w4];
        float vv[4] = {v.x, v.y, v.z, v.w};
#pragma unroll
        for (int j = 0; j < 4; ++j) {
            int wbase = (w4 * 4 + j) * Mk;  // wave-uniform -> scalar loads
#pragma unroll
            for (int k = 0; k < Mk; ++k) {
                xr[k] += vv[j] * twc[wbase + k];
                xi[k] -= vv[j] * tws[wbase + k];
            }
        }
    }
    float* op = Xxw + (size_t)r * (2 * Mk);
#pragma unroll
    for (int k = 0; k < Mk; ++k) { op[2 * k] = xr[k]; op[2 * k + 1] = xi[k]; }
}

// ------- DFT along H of x-modes -> Xfx[b][m][ky] (all batches) -------
__global__ __launch_bounds__(256) void k_xdfth(const float* __restrict__ Xxw,
                                               float* __restrict__ Xfx,
                                               const float* __restrict__ tc,
                                               const float* __restrict__ ts) {
    int t = blockIdx.x * 256 + threadIdx.x;  // < 4608
    if (t >= 16 * 288) return;
    int ky = t % Mk;
    int m  = (t / Mk) % NM;
    int b  = t / 288;
    int kx = (m < Mk) ? m : (232 + m);
    const float* base = Xxw + (size_t)b * Hn * 2 * Mk + 2 * ky;
    float ar = 0.f, ai = 0.f;
    for (int hh = 0; hh < Hn; ++hh) {
        float vr = base[hh * 2 * Mk];
        float vi = base[hh * 2 * Mk + 1];
        int idx = (kx * hh) & 255;
        float c = tc[idx], s = ts[idx];
        ar += vr * c + vi * s;   // * e^{-i theta}
        ai += vi * c - vr * s;
    }
    Xfx[2 * t] = ar;
    Xfx[2 * t + 1] = ai;
}

// ------- layer-0 mix: Z[b][ky][o][m] from Xfx (lift folded in) -------
__global__ __launch_bounds__(256, 2) void k_mix0(const float* __restrict__ Xfx,
                                                 const float* __restrict__ scwT,
                                                 const float* __restrict__ w0,
                                                 const float* __restrict__ b0v,
                                                 float* __restrict__ Z, int b0) {
    __shared__ float red[512];
    int blk = blockIdx.x;
    int b = blk / 288, mk = blk % 288;
    int m = mk / Mk, ky = mk % Mk;
    int t = threadIdx.x;
    int o = t & 63, q = t >> 6;
    float xr = Xfx[((b0 + b) * 288 + mk) * 2];
    float xi = Xfx[((b0 + b) * 288 + mk) * 2 + 1];
    int j = (m < Mk) ? 0 : 1;
    int kxw = (m < Mk) ? m : (m - Mk);
    const float* wb = scwT + ((size_t)((j * Mk + kxw) * Mk + ky) * 4096 + (q * 16) * 64 + o) * 2;
    float zr = 0.f, zi = 0.f;
#pragma unroll
    for (int ii = 0; ii < 16; ++ii) {
        int i = q * 16 + ii;
        float ar = w0[i] * xr, ai = w0[i] * xi;
        if (mk == 0) ar += 65536.0f * b0v[i];
        float wr = wb[ii * 128], wi = wb[ii * 128 + 1];
        zr += ar * wr - ai * wi;
        zi += ar * wi + ai * wr;
    }
    red[t * 2] = zr; red[t * 2 + 1] = zi;
    __syncthreads();
    if (t < 64) {
        float sr = red[t * 2] + red[(t + 64) * 2] + red[(t + 128) * 2] + red[(t + 192) * 2];
        float si = red[t * 2 + 1] + red[(t + 64) * 2 + 1] + red[(t + 128) * 2 + 1] + red[(t + 192) * 2 + 1];
        const float sc = 2.0f / 65536.0f;  // hermitian 2x + 1/(H*W)
        float2* zo = (float2*)Z + (((size_t)b * Mk + ky) * 64 + t) * 24 + m;
        *zo = make_float2(sr * sc, si * sc);
    }
}

// ------- layers 1..3: dft_h(Xw) + mode mix, fused. Xw layout [b][ky][hh][i][2]
__global__ __launch_bounds__(256, 2) void k_dfthmix(const float* __restrict__ Xw,
                                                    const float* __restrict__ scwT,
                                                    float* __restrict__ Z,
                                                    const float* __restrict__ tcs, int l) {
    __shared__ float red[512];
    __shared__ float xf[128];
    int blk = blockIdx.x;
    int b = blk / 288, mk = blk % 288;
    int m = mk / Mk, ky = mk % Mk;
    int t = threadIdx.x;
    int kx = (m < Mk) ? m : (232 + m);
    int i = t & 63, q = t >> 6;
    // phase 1: Xf[i] = sum_hh Xw[ky][hh][i] * e^{-i kx hh}  (coalesced float2)
    const float2* Xp = (const float2*)Xw + ((size_t)b * Mk + ky) * 16384 + i;
    const float2* tc2 = (const float2*)tcs;
    float ar0 = 0.f, ai0 = 0.f, ar1 = 0.f, ai1 = 0.f;
    for (int hc = 0; hc < 64; hc += 2) {
        int hh = q * 64 + hc;
        float2 v0 = Xp[(size_t)hh * 64];
        float2 v1 = Xp[(size_t)(hh + 1) * 64];
        float2 c0 = tc2[(kx * hh) & 255];
        float2 c1 = tc2[(kx * (hh + 1)) & 255];
        ar0 += v0.x * c0.x + v0.y * c0.y;
        ai0 += v0.y * c0.x - v0.x * c0.y;
        ar1 += v1.x * c1.x + v1.y * c1.y;
        ai1 += v1.y * c1.x - v1.x * c1.y;
    }
    red[t * 2] = ar0 + ar1; red[t * 2 + 1] = ai0 + ai1;
    __syncthreads();
    if (t < 64) {
        xf[t * 2]     = red[t * 2] + red[(t + 64) * 2] + red[(t + 128) * 2] + red[(t + 192) * 2];
        xf[t * 2 + 1] = red[t * 2 + 1] + red[(t + 64) * 2 + 1] + red[(t + 128) * 2 + 1] + red[(t + 192) * 2 + 1];
    }
    __syncthreads();
    // phase 2: Z[o] = sum_i W[i][o] * Xf[i]  (contiguous float2 weight reads)
    int o = t & 63;
    int j = (m < Mk) ? 0 : 1;
    int kxw = (m < Mk) ? m : (m - Mk);
    const float* wb = scwT + ((size_t)(((l * 2 + j) * Mk + kxw) * Mk + ky) * 4096 + (q * 16) * 64 + o) * 2;
    float zr = 0.f, zi = 0.f;
#pragma unroll
    for (int ii = 0; ii < 16; ++ii) {
        float br = xf[(q * 16 + ii) * 2], bi = xf[(q * 16 + ii) * 2 + 1];
        float wr = wb[ii * 128], wi = wb[ii * 128 + 1];
        zr += br * wr - bi * wi;
        zi += br * wi + bi * wr;
    }
    __syncthreads();
    red[t * 2] = zr; red[t * 2 + 1] = zi;
    __syncthreads();
    if (t < 64) {
        float sr = red[t * 2] + red[(t + 64) * 2] + red[(t + 128) * 2] + red[(t + 192) * 2];
        float si = red[t * 2 + 1] + red[(t + 64) * 2 + 1] + red[(t + 128) * 2 + 1] + red[(t + 192) * 2 + 1];
        const float sc = 2.0f / 65536.0f;
        float2* zo = (float2*)Z + (((size_t)b * Mk + ky) * 64 + t) * 24 + m;
        *zo = make_float2(sr * sc, si * sc);
    }
}

// ------- fused A: idft_h + idft_w + pointwise + gelu + dft_w(h_new) -------
// xh/hn may alias (in-place, per-fiber, reads precede writes).
// LDS union: Ysh [0,6144) + csm [6144,6336) alive through phase b;
// hsh [0,34816) alive from phase d (barrier-protected alias).
__global__ __launch_bounds__(256) void k_fusedA(const float* xh,
        const float* __restrict__ Zb, const float* __restrict__ pww,
        const float* __restrict__ pwb, const float* __restrict__ w0,
        const float* __restrict__ b0v, float* hn, float* __restrict__ XwOut,
        const float* __restrict__ tcs, const float* __restrict__ tw2,
        int l, int first) {
    __shared__ __align__(16) char smem[34816];
    float* Ysh = (float*)smem;
    float* csm = (float*)(smem + 6144);
    unsigned short* hsh = (unsigned short*)smem;  // bf16, padded stride 272
    int b  = blockIdx.x >> 8;
    int hh = blockIdx.x & 255;
    int w  = threadIdx.x;
    const float2* tc2 = (const float2*)tcs;
    // per-block H-twiddles for the 24 retained kx modes
    if (w < NM) {
        int kx = (w < Mk) ? w : (232 + w);
        float2 cs = tc2[(kx * hh) & 255];
        csm[2 * w] = cs.x; csm[2 * w + 1] = cs.y;
    }
    __syncthreads();
    const float* Zbb = Zb + (size_t)b * 36864;
    const float4* cs4 = (const float4*)csm;
#pragma unroll
    for (int r3 = 0; r3 < 3; ++r3) {
        int p = w + 256 * r3;          // p = o*12 + ky
        int o = p / Mk, ky = p % Mk;
        const float4* zv = (const float4*)(Zbb + ((size_t)ky * 64 + o) * 48);
        float yr = 0.f, yi = 0.f;
#pragma unroll
        for (int mm = 0; mm < 12; ++mm) {   // two modes per float4
            float4 z  = zv[mm];
            float4 cc = cs4[mm];
            yr += z.x * cc.x - z.y * cc.y + z.z * cc.z - z.w * cc.w;
            yi += z.x * cc.y + z.y * cc.x + z.z * cc.w + z.w * cc.z;
        }
        Ysh[p * 2] = yr; Ysh[p * 2 + 1] = yi;
    }
    __syncthreads();
    float cwv[Mk], swv[Mk];
#pragma unroll
    for (int k = 0; k < Mk; ++k) {
        float2 cs = tc2[(k * w) & 255];
        cwv[k] = cs.x; swv[k] = cs.y;
    }
    float acc[Cn];
#pragma unroll
    for (int o = 0; o < Cn; ++o) {
        const float4* yv = (const float4*)(Ysh + o * 24);
        float4 q0 = yv[0];
        float a = pwb[l * Cn + o] + 0.5f * q0.x + q0.z * cwv[1] - q0.w * swv[1];
#pragma unroll
        for (int j = 1; j < 6; ++j) {
            float4 qj = yv[j];
            a += qj.x * cwv[2 * j] - qj.y * swv[2 * j]
               + qj.z * cwv[2 * j + 1] - qj.w * swv[2 * j + 1];
        }
        acc[o] = a;
    }
    __syncthreads();   // Ysh/csm reads done; hsh may overwrite after this
    const float* wwb = pww + l * Cn * Cn;
    if (first) {
        float xv = xh[(size_t)b * HW + hh * 256 + w];
#pragma unroll 1
        for (int ic = 0; ic < 4; ++ic) {
            float v[16];
#pragma unroll
            for (int j2 = 0; j2 < 16; ++j2)
                v[j2] = w0[ic * 16 + j2] * xv + b0v[ic * 16 + j2];
#pragma unroll
            for (int o = 0; o < Cn; ++o) {
                const float* wr = wwb + o * Cn + ic * 16;  // uniform -> s_load
                float a = acc[o];
#pragma unroll
                for (int j2 = 0; j2 < 16; ++j2) a += v[j2] * wr[j2];
                acc[o] = a;
            }
        }
    } else {
        const float* hb = xh + (size_t)b * Cn * HW + hh * 256 + w;
#pragma unroll 1
        for (int ic = 0; ic < 4; ++ic) {
            float v[16];
#pragma unroll
            for (int j2 = 0; j2 < 16; ++j2)
                v[j2] = hb[(size_t)(ic * 16 + j2) * HW];
#pragma unroll
            for (int o = 0; o < Cn; ++o) {
                const float* wr = wwb + o * Cn + ic * 16;
                float a = acc[o];
#pragma unroll
                for (int j2 = 0; j2 < 16; ++j2) a += v[j2] * wr[j2];
                acc[o] = a;
            }
        }
    }
    // gelu + store h (fp32) + stage bf16 into LDS; acc dies here -> no spill
    float* ob = hn + (size_t)b * Cn * HW + hh * 256 + w;
#pragma unroll
    for (int o = 0; o < Cn; ++o) {
        float g = gelu_exact(acc[o]);
        ob[(size_t)o * HW] = g;
        hsh[o * 272 + w] = f2bf(g);
    }
    __syncthreads();
    // DFT along W of h_new -> Xw[b][ky][hh][o][2]  (bf16 source, x1-path only)
    float2* Xwb = (float2*)XwOut + (size_t)b * 196608;
#pragma unroll 1
    for (int r2 = 0; r2 < 3; ++r2) {
        int p = w + 256 * r2;          // p = o2*12 + ky, < 768
        int o2 = p / Mk, ky = p % Mk;
        const uint4* row4 = (const uint4*)(hsh + o2 * 272);       // 544B rows, 16-aligned
        const float4* tw4 = ((const float4*)tw2) + ky * 128;      // [k][w] packed (c,s)
        float xr0 = 0.f, xr1 = 0.f, xi0 = 0.f, xi1 = 0.f;
        for (int c8 = 0; c8 < 32; ++c8) {
            uint4 u = row4[c8];        // 8 bf16
            float4 t0 = tw4[c8 * 4], t1 = tw4[c8 * 4 + 1];
            float4 t2 = tw4[c8 * 4 + 2], t3 = tw4[c8 * 4 + 3];
            float h0 = bfbits(u.x << 16), h1 = bfbits(u.x & 0xffff0000u);
            float h2 = bfbits(u.y << 16), h3 = bfbits(u.y & 0xffff0000u);
            float h4 = bfbits(u.z << 16), h5 = bfbits(u.z & 0xffff0000u);
            float h6 = bfbits(u.w << 16), h7 = bfbits(u.w & 0xffff0000u);
            xr0 += h0 * t0.x; xi0 += h0 * t0.y; xr1 += h1 * t0.z; xi1 += h1 * t0.w;
            xr0 += h2 * t1.x; xi0 += h2 * t1.y; xr1 += h3 * t1.z; xi1 += h3 * t1.w;
            xr0 += h4 * t2.x; xi0 += h4 * t2.y; xr1 += h5 * t2.z; xi1 += h5 * t2.w;
            xr0 += h6 * t3.x; xi0 += h6 * t3.y; xr1 += h7 * t3.z; xi1 += h7 * t3.w;
        }
        Xwb[((size_t)ky * 256 + hh) * 64 + o2] = make_float2(xr0 + xr1, -(xi0 + xi1));
    }
}

// ------- fused B (layer 3): idft + pointwise + fc1/gelu/fc2 (d-tiled) -------
__global__ __launch_bounds__(256) void k_fusedB(const float* __restrict__ h,
        const float* __restrict__ Zb, const float* __restrict__ pww,
        const float* __restrict__ pwb, const float* __restrict__ fc1w,
        const float* __restrict__ fc1b, const float* __restrict__ fc2w,
        const float* __restrict__ fc2b, float* __restrict__ outp,
        const float* __restrict__ tcs) {
    __shared__ __align__(16) float Ysh[1536];
    __shared__ __align__(16) float csm[48];
    int b  = blockIdx.x >> 8;
    int hh = blockIdx.x & 255;
    int w  = threadIdx.x;
    const float2* tc2 = (const float2*)tcs;
    if (w < NM) {
        int kx = (w < Mk) ? w : (232 + w);
        float2 cs = tc2[(kx * hh) & 255];
        csm[2 * w] = cs.x; csm[2 * w + 1] = cs.y;
    }
    __syncthreads();
    const float* Zbb = Zb + (size_t)b * 36864;
    const float4* cs4 = (const float4*)csm;
#pragma unroll
    for (int r3 = 0; r3 < 3; ++r3) {
        int p = w + 256 * r3;
        int o = p / Mk, ky = p % Mk;
        const float4* zv = (const float4*)(Zbb + ((size_t)ky * 64 + o) * 48);
        float yr = 0.f, yi = 0.f;
#pragma unroll
        for (int mm = 0; mm < 12; ++mm) {
            float4 z  = zv[mm];
            float4 cc = cs4[mm];
            yr += z.x * cc.x - z.y * cc.y + z.z * cc.z - z.w * cc.w;
            yi += z.x * cc.y + z.y * cc.x + z.z * cc.w + z.w * cc.z;
        }
        Ysh[p * 2] = yr; Ysh[p * 2 + 1] = yi;
    }
    __syncthreads();
    float cwv[Mk], swv[Mk];
#pragma unroll
    for (int k = 0; k < Mk; ++k) {
        float2 cs = tc2[(k * w) & 255];
        cwv[k] = cs.x; swv[k] = cs.y;
    }
    float acc[Cn];
#pragma unroll
    for (int o = 0; o < Cn; ++o) {
        const float4* yv = (const float4*)(Ysh + o * 24);
        float4 q0 = yv[0];
        float a = pwb[3 * Cn + o] + 0.5f * q0.x + q0.z * cwv[1] - q0.w * swv[1];
#pragma unroll
        for (int j = 1; j < 6; ++j) {
            float4 qj = yv[j];
            a += qj.x * cwv[2 * j] - qj.y * swv[2 * j]
               + qj.z * cwv[2 * j + 1] - qj.w * swv[2 * j + 1];
        }
        acc[o] = a;
    }
    const float* wwb = pww + 3 * Cn * Cn;
    const float* hb = h + (size_t)b * Cn * HW + hh * 256 + w;
#pragma unroll 1
    for (int ic = 0; ic < 4; ++ic) {
        float v[16];
#pragma unroll
        for (int j2 = 0; j2 < 16; ++j2)
            v[j2] = hb[(size_t)(ic * 16 + j2) * HW];
#pragma unroll
        for (int o = 0; o < Cn; ++o) {
            const float* wr = wwb + o * Cn + ic * 16;
            float a = acc[o];
#pragma unroll
            for (int j2 = 0; j2 < 16; ++j2) a += v[j2] * wr[j2];
            acc[o] = a;
        }
    }
    // fc1 -> gelu -> fc2, d tiled by 32: 32 independent accumulators (ILP)
    float outv = fc2b[0];
#pragma unroll 1
    for (int dt = 0; dt < 4; ++dt) {
        float hid[32];
#pragma unroll
        for (int j2 = 0; j2 < 32; ++j2) hid[j2] = fc1b[dt * 32 + j2];
#pragma unroll 8
        for (int o = 0; o < Cn; ++o) {
            float a = acc[o];
            const float* wr = fc1w + o * FCH + dt * 32;  // uniform -> s_load
#pragma unroll
            for (int j2 = 0; j2 < 32; ++j2) hid[j2] += a * wr[j2];
        }
#pragma unroll
        for (int j2 = 0; j2 < 32; ++j2)
            outv += gelu_exact(hid[j2]) * fc2w[dt * 32 + j2];
    }
    outp[(size_t)b * HW + hh * 256 + w] = outv;
}

extern "C" void kernel_launch(void* const* d_in, const int* in_sizes, int n_in,
                              void* d_out, int out_size, void* d_ws, size_t ws_size,
                              hipStream_t stream) {
    const float* x    = (const float*)d_in[0];
    const float* fc0w = (const float*)d_in[1];
    const float* fc0b = (const float*)d_in[2];
    const float* scw  = (const float*)d_in[3];
    const float* pww  = (const float*)d_in[4];
    const float* pwb  = (const float*)d_in[5];
    const float* fc1w = (const float*)d_in[6];
    const float* fc1b = (const float*)d_in[7];
    const float* fc2w = (const float*)d_in[8];
    const float* fc2b = (const float*)d_in[9];
    float* out = (float*)d_out;
    float* ws  = (float*)d_ws;

    // base: tables 13312 + Xfx 9216 + scwT 9,437,184 = 9,459,712 floats
    // per batch: h 4,194,304 + Xw 393,216 + Z 36,864 = 4,624,384 floats
    const size_t basef = 9459712;
    const size_t perbf = 4624384;
    int bc = 0;
    for (int cand = 16; cand >= 1; cand >>= 1)
        if ((basef + perbf * (size_t)cand) * 4 <= ws_size) { bc = cand; break; }
    if (bc == 0) return;  // diagnosable: zero output

    float* tabc = ws;
    float* tabs = tabc + 256;
    float* twc  = tabs + 256;
    float* tws_ = twc + 3072;
    float* tcs  = tws_ + 3072;          // float2[256]  -> 512 floats
    float* tw2  = tcs + 512;            // float2[3072] -> 6144 floats, [k][w]
    float* Xfx  = tw2 + 6144;           // 9216
    float* scwT = Xfx + 9216;           // 9,437,184
    float* hbuf = ws + basef;           // bc*4,194,304 (also Xxw temp 98,304)
    float* Xw   = hbuf + (size_t)bc * 4194304;
    float* Zb   = Xw + (size_t)bc * 393216;

    k_init_tables<<<1, 256, 0, stream>>>(tabc, tabs, twc, tws_, tcs, tw2);
    k_prep_w<<<9216, 256, 0, stream>>>(scw, scwT);
    k_dftw_x<<<64, 64, 0, stream>>>(x, hbuf, twc, tws_);
    k_xdfth<<<18, 256, 0, stream>>>(hbuf, Xfx, tabc, tabs);

    for (int b0 = 0; b0 < 16; b0 += bc) {
        k_mix0<<<bc * 288, 256, 0, stream>>>(Xfx, scwT, fc0w, fc0b, Zb, b0);
        k_fusedA<<<bc * 256, 256, 0, stream>>>(x + (size_t)b0 * HW, Zb, pww, pwb,
                                               fc0w, fc0b, hbuf, Xw,
                                               tcs, tw2, 0, 1);
        for (int l = 1; l <= 2; ++l) {
            k_dfthmix<<<bc * 288, 256, 0, stream>>>(Xw, scwT, Zb, tcs, l);
            k_fusedA<<<bc * 256, 256, 0, stream>>>(hbuf, Zb, pww, pwb,
                                                   fc0w, fc0b, hbuf, Xw,
                                                   tcs, tw2, l, 0);
        }
        k_dfthmix<<<bc * 288, 256, 0, stream>>>(Xw, scwT, Zb, tcs, 3);
        k_fusedB<<<bc * 256, 256, 0, stream>>>(hbuf, Zb, pww, pwb, fc1w, fc1b,
                                               fc2w, fc2b, out + (size_t)b0 * HW,
                                               tcs);
    }
}

// Round 3
// 3186.544 us; speedup vs baseline: 1.5399x; 1.5399x over previous
//
#include <hip/hip_runtime.h>
#include <hip/hip_bf16.h>
#include <math.h>

#define Hn 256
#define Wn 256
#define Cn 64
#define Mk 12
#define NM 24
#define FCH 128
#define HW 65536

using half8 = __attribute__((ext_vector_type(8))) _Float16;
using f32x4 = __attribute__((ext_vector_type(4))) float;

__device__ __forceinline__ float gelu_exact(float x) {
    return 0.5f * x * (1.0f + erff(x * 0.7071067811865476f));
}

// ---------------- tables ----------------
// tc/ts: cos/sin(i*step); twc/tws: [w][k] (legacy, used by k_dftw_x)
// tcs: packed (c,s) float2[256]
// bfr: MFMA B-fragment twiddle table, fp16, [kstep(8)][ntile(3)][lane(64)][j(8)]
//      col c = n*16+(lane&15); ky=c>>1; p=c&1; k = s*32 + ((lane>>4)&3)*8 + j
//      val = p ? -sin(2pi*ky*k/256) : cos(2pi*ky*k/256)
__global__ __launch_bounds__(256) void k_init_tables(float* tc, float* ts,
                                                     float* twc, float* tws,
                                                     float* tcs,
                                                     unsigned short* bfr) {
    int i = threadIdx.x;  // 0..255
    const float step = 0.024543692606170259f;  // 2*pi/256
    float c = cosf(i * step), s = sinf(i * step);
    tc[i] = c; ts[i] = s;
    tcs[2 * i] = c; tcs[2 * i + 1] = s;
    for (int k = 0; k < Mk; ++k) {
        int idx = (i * k) & 255;
        twc[i * Mk + k] = cosf(idx * step);
        tws[i * Mk + k] = sinf(idx * step);
    }
    for (int e = i; e < 12288; e += 256) {
        int j  = e & 7;
        int l  = (e >> 3) & 63;
        int sn = e >> 9;            // s*3 + n, 0..23
        int col = (sn % 3) * 16 + (l & 15);
        int ky = col >> 1, p = col & 1;
        int k  = (sn / 3) * 32 + ((l >> 4) & 3) * 8 + j;
        int idx = (ky * k) & 255;
        float v = p ? -sinf(idx * step) : cosf(idx * step);
        _Float16 hv = (_Float16)v;
        bfr[e] = __builtin_bit_cast(unsigned short, hv);
    }
}

// ------- spectral weight transpose: scw[l,j,i,o,kx,ky,2] -> scwT[l,j,kx,ky,i,o,2]
__global__ __launch_bounds__(256) void k_prep_w(const float* __restrict__ scw,
                                                float* __restrict__ scwT) {
    int t = blockIdx.x * 256 + threadIdx.x;  // < 2,359,296
    int o  = t & 63;
    int i  = (t >> 6) & 63;
    int r  = t >> 12;           // lj*72 + kx*6 + u, r < 576
    int u  = r % 6;
    int kx = (r / 6) % 12;
    int lj = r / 72;            // 0..7
    int ky = 2 * u;
    size_t in_idx = ((((size_t)lj * 64 + i) * 64 + o) * 144) + kx * Mk + ky;  // even
    float4 v = *(const float4*)(scw + 2 * in_idx);
    size_t o0 = ((((size_t)(lj * 12 + kx) * Mk + ky) * 64 + i) * 64 + o);
    size_t o1 = ((((size_t)(lj * 12 + kx) * Mk + ky + 1) * 64 + i) * 64 + o);
    *(float2*)(scwT + 2 * o0) = make_float2(v.x, v.y);
    *(float2*)(scwT + 2 * o1) = make_float2(v.z, v.w);
}

// ------- DFT along W of x (all 16 batches, 4096 rows), lane-per-row -------
__global__ __launch_bounds__(64) void k_dftw_x(const float* __restrict__ x,
                                               float* __restrict__ Xxw,
                                               const float* __restrict__ twc,
                                               const float* __restrict__ tws) {
    int r = blockIdx.x * 64 + threadIdx.x;  // 0..4095
    const float* hp = x + (size_t)r * Wn;
    float xr[Mk], xi[Mk];
#pragma unroll
    for (int k = 0; k < Mk; ++k) { xr[k] = 0.f; xi[k] = 0.f; }
    for (int w4 = 0; w4 < 64; ++w4) {
        float4 v = ((const float4*)hp)[w4];
        float vv[4] = {v.x, v.y, v.z, v.w};
#pragma unroll
        for (int j = 0; j < 4; ++j) {
            int wbase = (w4 * 4 + j) * Mk;  // wave-uniform -> scalar loads
#pragma unroll
            for (int k = 0; k < Mk; ++k) {
                xr[k] += vv[j] * twc[wbase + k];
                xi[k] -= vv[j] * tws[wbase + k];
            }
        }
    }
    float* op = Xxw + (size_t)r * (2 * Mk);
#pragma unroll
    for (int k = 0; k < Mk; ++k) { op[2 * k] = xr[k]; op[2 * k + 1] = xi[k]; }
}

// ------- DFT along H of x-modes -> Xfx[b][m][ky] (all batches) -------
__global__ __launch_bounds__(256) void k_xdfth(const float* __restrict__ Xxw,
                                               float* __restrict__ Xfx,
                                               const float* __restrict__ tc,
                                               const float* __restrict__ ts) {
    int t = blockIdx.x * 256 + threadIdx.x;  // < 4608
    if (t >= 16 * 288) return;
    int ky = t % Mk;
    int m  = (t / Mk) % NM;
    int b  = t / 288;
    int kx = (m < Mk) ? m : (232 + m);
    const float* base = Xxw + (size_t)b * Hn * 2 * Mk + 2 * ky;
    float ar = 0.f, ai = 0.f;
    for (int hh = 0; hh < Hn; ++hh) {
        float vr = base[hh * 2 * Mk];
        float vi = base[hh * 2 * Mk + 1];
        int idx = (kx * hh) & 255;
        float c = tc[idx], s = ts[idx];
        ar += vr * c + vi * s;   // * e^{-i theta}
        ai += vi * c - vr * s;
    }
    Xfx[2 * t] = ar;
    Xfx[2 * t + 1] = ai;
}

// ------- layer-0 mix: Z[b][ky][o][m] from Xfx (lift folded in) -------
__global__ __launch_bounds__(256, 2) void k_mix0(const float* __restrict__ Xfx,
                                                 const float* __restrict__ scwT,
                                                 const float* __restrict__ w0,
                                                 const float* __restrict__ b0v,
                                                 float* __restrict__ Z, int b0) {
    __shared__ float red[512];
    int blk = blockIdx.x;
    int b = blk / 288, mk = blk % 288;
    int m = mk / Mk, ky = mk % Mk;
    int t = threadIdx.x;
    int o = t & 63, q = t >> 6;
    float xr = Xfx[((b0 + b) * 288 + mk) * 2];
    float xi = Xfx[((b0 + b) * 288 + mk) * 2 + 1];
    int j = (m < Mk) ? 0 : 1;
    int kxw = (m < Mk) ? m : (m - Mk);
    const float* wb = scwT + ((size_t)((j * Mk + kxw) * Mk + ky) * 4096 + (q * 16) * 64 + o) * 2;
    float zr = 0.f, zi = 0.f;
#pragma unroll
    for (int ii = 0; ii < 16; ++ii) {
        int i = q * 16 + ii;
        float ar = w0[i] * xr, ai = w0[i] * xi;
        if (mk == 0) ar += 65536.0f * b0v[i];
        float wr = wb[ii * 128], wi = wb[ii * 128 + 1];
        zr += ar * wr - ai * wi;
        zi += ar * wi + ai * wr;
    }
    red[t * 2] = zr; red[t * 2 + 1] = zi;
    __syncthreads();
    if (t < 64) {
        float sr = red[t * 2] + red[(t + 64) * 2] + red[(t + 128) * 2] + red[(t + 192) * 2];
        float si = red[t * 2 + 1] + red[(t + 64) * 2 + 1] + red[(t + 128) * 2 + 1] + red[(t + 192) * 2 + 1];
        const float sc = 2.0f / 65536.0f;  // hermitian 2x + 1/(H*W)
        float2* zo = (float2*)Z + (((size_t)b * Mk + ky) * 64 + t) * 24 + m;
        *zo = make_float2(sr * sc, si * sc);
    }
}

// ------- layers 1..3: dft_h(Xw) + mode mix, fused. Xw layout [b][ky][hh][i][2]
__global__ __launch_bounds__(256, 2) void k_dfthmix(const float* __restrict__ Xw,
                                                    const float* __restrict__ scwT,
                                                    float* __restrict__ Z,
                                                    const float* __restrict__ tcs, int l) {
    __shared__ float red[512];
    __shared__ float xf[128];
    int blk = blockIdx.x;
    int b = blk / 288, mk = blk % 288;
    int m = mk / Mk, ky = mk % Mk;
    int t = threadIdx.x;
    int kx = (m < Mk) ? m : (232 + m);
    int i = t & 63, q = t >> 6;
    // phase 1: Xf[i] = sum_hh Xw[ky][hh][i] * e^{-i kx hh}  (coalesced float2)
    const float2* Xp = (const float2*)Xw + ((size_t)b * Mk + ky) * 16384 + i;
    const float2* tc2 = (const float2*)tcs;
    float ar0 = 0.f, ai0 = 0.f, ar1 = 0.f, ai1 = 0.f;
    for (int hc = 0; hc < 64; hc += 2) {
        int hh = q * 64 + hc;
        float2 v0 = Xp[(size_t)hh * 64];
        float2 v1 = Xp[(size_t)(hh + 1) * 64];
        float2 c0 = tc2[(kx * hh) & 255];
        float2 c1 = tc2[(kx * (hh + 1)) & 255];
        ar0 += v0.x * c0.x + v0.y * c0.y;
        ai0 += v0.y * c0.x - v0.x * c0.y;
        ar1 += v1.x * c1.x + v1.y * c1.y;
        ai1 += v1.y * c1.x - v1.x * c1.y;
    }
    red[t * 2] = ar0 + ar1; red[t * 2 + 1] = ai0 + ai1;
    __syncthreads();
    if (t < 64) {
        xf[t * 2]     = red[t * 2] + red[(t + 64) * 2] + red[(t + 128) * 2] + red[(t + 192) * 2];
        xf[t * 2 + 1] = red[t * 2 + 1] + red[(t + 64) * 2 + 1] + red[(t + 128) * 2 + 1] + red[(t + 192) * 2 + 1];
    }
    __syncthreads();
    // phase 2: Z[o] = sum_i W[i][o] * Xf[i]  (contiguous float2 weight reads)
    int o = t & 63;
    int j = (m < Mk) ? 0 : 1;
    int kxw = (m < Mk) ? m : (m - Mk);
    const float* wb = scwT + ((size_t)(((l * 2 + j) * Mk + kxw) * Mk + ky) * 4096 + (q * 16) * 64 + o) * 2;
    float zr = 0.f, zi = 0.f;
#pragma unroll
    for (int ii = 0; ii < 16; ++ii) {
        float br = xf[(q * 16 + ii) * 2], bi = xf[(q * 16 + ii) * 2 + 1];
        float wr = wb[ii * 128], wi = wb[ii * 128 + 1];
        zr += br * wr - bi * wi;
        zi += br * wi + bi * wr;
    }
    __syncthreads();
    red[t * 2] = zr; red[t * 2 + 1] = zi;
    __syncthreads();
    if (t < 64) {
        float sr = red[t * 2] + red[(t + 64) * 2] + red[(t + 128) * 2] + red[(t + 192) * 2];
        float si = red[t * 2 + 1] + red[(t + 64) * 2 + 1] + red[(t + 128) * 2 + 1] + red[(t + 192) * 2 + 1];
        const float sc = 2.0f / 65536.0f;
        float2* zo = (float2*)Z + (((size_t)b * Mk + ky) * 64 + t) * 24 + m;
        *zo = make_float2(sr * sc, si * sc);
    }
}

// ------- fused A: idft_h + idft_w + pointwise + gelu + dft_w(h_new, MFMA) -------
// xh/hn may alias (in-place, per-fiber, reads precede writes).
// LDS union (32 KiB -> 5 blocks/CU): Ysh [0,6144) + csm [6144,6336) alive through
// phase b; hsh fp16 [64][256] XOR-swizzled, full 32 KiB, alive from staging
// (barrier-protected alias).
__global__ __launch_bounds__(256) void k_fusedA(const float* xh,
        const float* __restrict__ Zb, const float* __restrict__ pww,
        const float* __restrict__ pwb, const float* __restrict__ w0,
        const float* __restrict__ b0v, float* hn, float* __restrict__ XwOut,
        const float* __restrict__ tcs, const unsigned short* __restrict__ bfr,
        int l, int first) {
    __shared__ __align__(16) char smem[32768];
    float* Ysh = (float*)smem;
    float* csm = (float*)(smem + 6144);
    _Float16* hsf = (_Float16*)smem;
    int b  = blockIdx.x >> 8;
    int hh = blockIdx.x & 255;
    int w  = threadIdx.x;
    const float2* tc2 = (const float2*)tcs;
    // per-block H-twiddles for the 24 retained kx modes
    if (w < NM) {
        int kx = (w < Mk) ? w : (232 + w);
        float2 cs = tc2[(kx * hh) & 255];
        csm[2 * w] = cs.x; csm[2 * w + 1] = cs.y;
    }
    __syncthreads();
    const float* Zbb = Zb + (size_t)b * 36864;
    const float4* cs4 = (const float4*)csm;
#pragma unroll
    for (int r3 = 0; r3 < 3; ++r3) {
        int p = w + 256 * r3;          // p = o*12 + ky
        int o = p / Mk, ky = p % Mk;
        const float4* zv = (const float4*)(Zbb + ((size_t)ky * 64 + o) * 48);
        float yr = 0.f, yi = 0.f;
#pragma unroll
        for (int mm = 0; mm < 12; ++mm) {   // two modes per float4
            float4 z  = zv[mm];
            float4 cc = cs4[mm];
            yr += z.x * cc.x - z.y * cc.y + z.z * cc.z - z.w * cc.w;
            yi += z.x * cc.y + z.y * cc.x + z.z * cc.w + z.w * cc.z;
        }
        Ysh[p * 2] = yr; Ysh[p * 2 + 1] = yi;
    }
    __syncthreads();
    float cwv[Mk], swv[Mk];
#pragma unroll
    for (int k = 0; k < Mk; ++k) {
        float2 cs = tc2[(k * w) & 255];
        cwv[k] = cs.x; swv[k] = cs.y;
    }
    float acc[Cn];
#pragma unroll
    for (int o = 0; o < Cn; ++o) {
        const float4* yv = (const float4*)(Ysh + o * 24);
        float4 q0 = yv[0];
        float a = pwb[l * Cn + o] + 0.5f * q0.x + q0.z * cwv[1] - q0.w * swv[1];
#pragma unroll
        for (int j = 1; j < 6; ++j) {
            float4 qj = yv[j];
            a += qj.x * cwv[2 * j] - qj.y * swv[2 * j]
               + qj.z * cwv[2 * j + 1] - qj.w * swv[2 * j + 1];
        }
        acc[o] = a;
    }
    __syncthreads();   // Ysh/csm reads done; hsf may overwrite after this
    const float* wwb = pww + l * Cn * Cn;
    if (first) {
        float xv = xh[(size_t)b * HW + hh * 256 + w];
#pragma unroll 1
        for (int ic = 0; ic < 4; ++ic) {
            float v[16];
#pragma unroll
            for (int j2 = 0; j2 < 16; ++j2)
                v[j2] = w0[ic * 16 + j2] * xv + b0v[ic * 16 + j2];
#pragma unroll
            for (int o = 0; o < Cn; ++o) {
                const float* wr = wwb + o * Cn + ic * 16;  // uniform -> s_load
                float a = acc[o];
#pragma unroll
                for (int j2 = 0; j2 < 16; ++j2) a += v[j2] * wr[j2];
                acc[o] = a;
            }
        }
    } else {
        const float* hb = xh + (size_t)b * Cn * HW + hh * 256 + w;
#pragma unroll 1
        for (int ic = 0; ic < 4; ++ic) {
            float v[16];
#pragma unroll
            for (int j2 = 0; j2 < 16; ++j2)
                v[j2] = hb[(size_t)(ic * 16 + j2) * HW];
#pragma unroll
            for (int o = 0; o < Cn; ++o) {
                const float* wr = wwb + o * Cn + ic * 16;
                float a = acc[o];
#pragma unroll
                for (int j2 = 0; j2 < 16; ++j2) a += v[j2] * wr[j2];
                acc[o] = a;
            }
        }
    }
    // gelu + store h (fp32) + stage fp16 into LDS (XOR-swizzled); acc dies here
    float* ob = hn + (size_t)b * Cn * HW + hh * 256 + w;
#pragma unroll
    for (int o = 0; o < Cn; ++o) {
        float g = gelu_exact(acc[o]);
        ob[(size_t)o * HW] = g;
        hsf[o * 256 + (((w >> 3) ^ (o & 7)) << 3) + (w & 7)] = (_Float16)g;
    }
    __syncthreads();
    // MFMA W-DFT: C[64 o2][48 cols] = hsf(64x256 fp16) @ Bfrag(256x48 fp16)
    // col c = 2*ky + p; p==0 -> sum h*cos = xr, p==1 -> sum h*(-sin) = xi
    {
        int lane = w & 63, q = w >> 6;
        int arow = q * 16 + (lane & 15);
        int tgrp = (lane >> 4) & 3;
        const uint4* bt = (const uint4*)bfr;
        f32x4 ac0 = {0.f, 0.f, 0.f, 0.f};
        f32x4 ac1 = {0.f, 0.f, 0.f, 0.f};
        f32x4 ac2 = {0.f, 0.f, 0.f, 0.f};
#pragma unroll
        for (int s = 0; s < 8; ++s) {
            int abyte = (arow * 512 + s * 64 + tgrp * 16) ^ ((arow & 7) << 4);
            half8 af = __builtin_bit_cast(half8, *(const uint4*)(smem + abyte));
            half8 b0 = __builtin_bit_cast(half8, bt[(s * 3 + 0) * 64 + lane]);
            half8 b1 = __builtin_bit_cast(half8, bt[(s * 3 + 1) * 64 + lane]);
            half8 b2 = __builtin_bit_cast(half8, bt[(s * 3 + 2) * 64 + lane]);
            ac0 = __builtin_amdgcn_mfma_f32_16x16x32_f16(af, b0, ac0, 0, 0, 0);
            ac1 = __builtin_amdgcn_mfma_f32_16x16x32_f16(af, b1, ac1, 0, 0, 0);
            ac2 = __builtin_amdgcn_mfma_f32_16x16x32_f16(af, b2, ac2, 0, 0, 0);
        }
        // C layout: col = lane&15, row = (lane>>4)*4 + reg  (within 16x16 tile)
        float* Xwb = XwOut + (size_t)b * 393216;
        int rbase = q * 16 + (lane >> 4) * 4;
#pragma unroll
        for (int n = 0; n < 3; ++n) {
            f32x4 ac = (n == 0) ? ac0 : ((n == 1) ? ac1 : ac2);
            int col = n * 16 + (lane & 15);
            int ky = col >> 1, p = col & 1;
            float* dst = Xwb + (size_t)ky * 32768 + hh * 128 + rbase * 2 + p;
            dst[0] = ac[0]; dst[2] = ac[1]; dst[4] = ac[2]; dst[6] = ac[3];
        }
    }
}

// ------- fused B (layer 3): idft + pointwise + fc1/gelu/fc2 (d-tiled) -------
__global__ __launch_bounds__(256) void k_fusedB(const float* __restrict__ h,
        const float* __restrict__ Zb, const float* __restrict__ pww,
        const float* __restrict__ pwb, const float* __restrict__ fc1w,
        const float* __restrict__ fc1b, const float* __restrict__ fc2w,
        const float* __restrict__ fc2b, float* __restrict__ outp,
        const float* __restrict__ tcs) {
    __shared__ __align__(16) float Ysh[1536];
    __shared__ __align__(16) float csm[48];
    int b  = blockIdx.x >> 8;
    int hh = blockIdx.x & 255;
    int w  = threadIdx.x;
    const float2* tc2 = (const float2*)tcs;
    if (w < NM) {
        int kx = (w < Mk) ? w : (232 + w);
        float2 cs = tc2[(kx * hh) & 255];
        csm[2 * w] = cs.x; csm[2 * w + 1] = cs.y;
    }
    __syncthreads();
    const float* Zbb = Zb + (size_t)b * 36864;
    const float4* cs4 = (const float4*)csm;
#pragma unroll
    for (int r3 = 0; r3 < 3; ++r3) {
        int p = w + 256 * r3;
        int o = p / Mk, ky = p % Mk;
        const float4* zv = (const float4*)(Zbb + ((size_t)ky * 64 + o) * 48);
        float yr = 0.f, yi = 0.f;
#pragma unroll
        for (int mm = 0; mm < 12; ++mm) {
            float4 z  = zv[mm];
            float4 cc = cs4[mm];
            yr += z.x * cc.x - z.y * cc.y + z.z * cc.z - z.w * cc.w;
            yi += z.x * cc.y + z.y * cc.x + z.z * cc.w + z.w * cc.z;
        }
        Ysh[p * 2] = yr; Ysh[p * 2 + 1] = yi;
    }
    __syncthreads();
    float cwv[Mk], swv[Mk];
#pragma unroll
    for (int k = 0; k < Mk; ++k) {
        float2 cs = tc2[(k * w) & 255];
        cwv[k] = cs.x; swv[k] = cs.y;
    }
    float acc[Cn];
#pragma unroll
    for (int o = 0; o < Cn; ++o) {
        const float4* yv = (const float4*)(Ysh + o * 24);
        float4 q0 = yv[0];
        float a = pwb[3 * Cn + o] + 0.5f * q0.x + q0.z * cwv[1] - q0.w * swv[1];
#pragma unroll
        for (int j = 1; j < 6; ++j) {
            float4 qj = yv[j];
            a += qj.x * cwv[2 * j] - qj.y * swv[2 * j]
               + qj.z * cwv[2 * j + 1] - qj.w * swv[2 * j + 1];
        }
        acc[o] = a;
    }
    const float* wwb = pww + 3 * Cn * Cn;
    const float* hb = h + (size_t)b * Cn * HW + hh * 256 + w;
#pragma unroll 1
    for (int ic = 0; ic < 4; ++ic) {
        float v[16];
#pragma unroll
        for (int j2 = 0; j2 < 16; ++j2)
            v[j2] = hb[(size_t)(ic * 16 + j2) * HW];
#pragma unroll
        for (int o = 0; o < Cn; ++o) {
            const float* wr = wwb + o * Cn + ic * 16;
            float a = acc[o];
#pragma unroll
            for (int j2 = 0; j2 < 16; ++j2) a += v[j2] * wr[j2];
            acc[o] = a;
        }
    }
    // fc1 -> gelu -> fc2, d tiled by 32: 32 independent accumulators (ILP)
    float outv = fc2b[0];
#pragma unroll 1
    for (int dt = 0; dt < 4; ++dt) {
        float hid[32];
#pragma unroll
        for (int j2 = 0; j2 < 32; ++j2) hid[j2] = fc1b[dt * 32 + j2];
#pragma unroll 8
        for (int o = 0; o < Cn; ++o) {
            float a = acc[o];
            const float* wr = fc1w + o * FCH + dt * 32;  // uniform -> s_load
#pragma unroll
            for (int j2 = 0; j2 < 32; ++j2) hid[j2] += a * wr[j2];
        }
#pragma unroll
        for (int j2 = 0; j2 < 32; ++j2)
            outv += gelu_exact(hid[j2]) * fc2w[dt * 32 + j2];
    }
    outp[(size_t)b * HW + hh * 256 + w] = outv;
}

extern "C" void kernel_launch(void* const* d_in, const int* in_sizes, int n_in,
                              void* d_out, int out_size, void* d_ws, size_t ws_size,
                              hipStream_t stream) {
    const float* x    = (const float*)d_in[0];
    const float* fc0w = (const float*)d_in[1];
    const float* fc0b = (const float*)d_in[2];
    const float* scw  = (const float*)d_in[3];
    const float* pww  = (const float*)d_in[4];
    const float* pwb  = (const float*)d_in[5];
    const float* fc1w = (const float*)d_in[6];
    const float* fc1b = (const float*)d_in[7];
    const float* fc2w = (const float*)d_in[8];
    const float* fc2b = (const float*)d_in[9];
    float* out = (float*)d_out;
    float* ws  = (float*)d_ws;

    // base: tables 13312 + Xfx 9216 + scwT 9,437,184 = 9,459,712 floats
    // per batch: h 4,194,304 + Xw 393,216 + Z 36,864 = 4,624,384 floats
    const size_t basef = 9459712;
    const size_t perbf = 4624384;
    int bc = 0;
    for (int cand = 16; cand >= 1; cand >>= 1)
        if ((basef + perbf * (size_t)cand) * 4 <= ws_size) { bc = cand; break; }
    if (bc == 0) return;  // diagnosable: zero output

    float* tabc = ws;
    float* tabs = tabc + 256;
    float* twc  = tabs + 256;
    float* tws_ = twc + 3072;
    float* tcs  = tws_ + 3072;          // float2[256]  -> 512 floats
    float* bfr  = tcs + 512;            // fp16[12288] MFMA B-frag table -> 6144 floats
    float* Xfx  = bfr + 6144;           // 9216
    float* scwT = Xfx + 9216;           // 9,437,184
    float* hbuf = ws + basef;           // bc*4,194,304 (also Xxw temp 98,304)
    float* Xw   = hbuf + (size_t)bc * 4194304;
    float* Zb   = Xw + (size_t)bc * 393216;

    k_init_tables<<<1, 256, 0, stream>>>(tabc, tabs, twc, tws_, tcs,
                                         (unsigned short*)bfr);
    k_prep_w<<<9216, 256, 0, stream>>>(scw, scwT);
    k_dftw_x<<<64, 64, 0, stream>>>(x, hbuf, twc, tws_);
    k_xdfth<<<18, 256, 0, stream>>>(hbuf, Xfx, tabc, tabs);

    for (int b0 = 0; b0 < 16; b0 += bc) {
        k_mix0<<<bc * 288, 256, 0, stream>>>(Xfx, scwT, fc0w, fc0b, Zb, b0);
        k_fusedA<<<bc * 256, 256, 0, stream>>>(x + (size_t)b0 * HW, Zb, pww, pwb,
                                               fc0w, fc0b, hbuf, Xw,
                                               tcs, (const unsigned short*)bfr, 0, 1);
        for (int l = 1; l <= 2; ++l) {
            k_dfthmix<<<bc * 288, 256, 0, stream>>>(Xw, scwT, Zb, tcs, l);
            k_fusedA<<<bc * 256, 256, 0, stream>>>(hbuf, Zb, pww, pwb,
                                                   fc0w, fc0b, hbuf, Xw,
                                                   tcs, (const unsigned short*)bfr, l, 0);
        }
        k_dfthmix<<<bc * 288, 256, 0, stream>>>(Xw, scwT, Zb, tcs, 3);
        k_fusedB<<<bc * 256, 256, 0, stream>>>(hbuf, Zb, pww, pwb, fc1w, fc1b,
                                               fc2w, fc2b, out + (size_t)b0 * HW,
                                               tcs);
    }
}

// Round 4
// 3080.638 us; speedup vs baseline: 1.5928x; 1.0344x over previous
//
#include <hip/hip_runtime.h>
#include <hip/hip_bf16.h>
#include <math.h>

#define Hn 256
#define Wn 256
#define Cn 64
#define Mk 12
#define NM 24
#define FCH 128
#define HW 65536

using half8 = __attribute__((ext_vector_type(8))) _Float16;
using f32x4 = __attribute__((ext_vector_type(4))) float;

__device__ __forceinline__ float gelu_exact(float x) {
    return 0.5f * x * (1.0f + erff(x * 0.7071067811865476f));
}
__device__ __forceinline__ unsigned short f2h(float f) {
    _Float16 h = (_Float16)f;
    return __builtin_bit_cast(unsigned short, h);
}

// ---------------- tables ----------------
// tc/ts: cos/sin(i*step); twc/tws: [w][k] (legacy, k_dftw_x)
// tcs: packed (c,s) float2[256]
// bfr: fusedA W-DFT B-frag table fp16 [s(8)][n(2)][lane(64)][j(8)]
//      col = n*16+(lane&15); ky=col>>1; p=col&1; k = s*32+((lane>>4)&3)*8+j
//      val = p ? -sin(2pi*ky*k/256) : cos(2pi*ky*k/256)   (ky 12..15 unused)
// tfr: k_dfth H-DFT A-frag table fp16 [s(8)][mt(3)][lane(64)][j(8)]
//      row r = mt*16+(lane&15); hh = s*32+((lane>>4)&3)*8+j
//      r<24: m=r, val=cos(2pi*kx(m)*hh/256); r>=24: m=r-24, val=sin(...)
__global__ __launch_bounds__(256) void k_init_tables(float* tc, float* ts,
                                                     float* twc, float* tws,
                                                     float* tcs,
                                                     unsigned short* bfr,
                                                     unsigned short* tfr) {
    int i = threadIdx.x;  // 0..255
    const float step = 0.024543692606170259f;  // 2*pi/256
    float c = cosf(i * step), s = sinf(i * step);
    tc[i] = c; ts[i] = s;
    tcs[2 * i] = c; tcs[2 * i + 1] = s;
    for (int k = 0; k < Mk; ++k) {
        int idx = (i * k) & 255;
        twc[i * Mk + k] = cosf(idx * step);
        tws[i * Mk + k] = sinf(idx * step);
    }
    for (int e = i; e < 8192; e += 256) {
        int j  = e & 7;
        int l  = (e >> 3) & 63;
        int sn = e >> 9;            // s*2+n, 0..15
        int col = (sn & 1) * 16 + (l & 15);
        int ky = col >> 1, p = col & 1;
        int k  = (sn >> 1) * 32 + ((l >> 4) & 3) * 8 + j;
        int idx = (ky * k) & 255;
        float v = p ? -sinf(idx * step) : cosf(idx * step);
        bfr[e] = f2h(v);
    }
    for (int e = i; e < 12288; e += 256) {
        int j  = e & 7;
        int l  = (e >> 3) & 63;
        int sm = e >> 9;            // s*3+mt, 0..23
        int mt = sm % 3, s2 = sm / 3;
        int r  = mt * 16 + (l & 15);
        int hh = s2 * 32 + ((l >> 4) & 3) * 8 + j;
        int m  = (r < 24) ? r : (r - 24);
        int kx = (m < Mk) ? m : (232 + m);
        int idx = (kx * hh) & 255;
        float v = (r < 24) ? cosf(idx * step) : sinf(idx * step);
        tfr[e] = f2h(v);
    }
}

// ------- spectral weight transpose: scw[l,j,i,o,kx,ky,2] -> scwT[l,j,kx,ky,i,o,2]
__global__ __launch_bounds__(256) void k_prep_w(const float* __restrict__ scw,
                                                float* __restrict__ scwT) {
    int t = blockIdx.x * 256 + threadIdx.x;  // < 2,359,296
    int o  = t & 63;
    int i  = (t >> 6) & 63;
    int r  = t >> 12;           // lj*72 + kx*6 + u, r < 576
    int u  = r % 6;
    int kx = (r / 6) % 12;
    int lj = r / 72;            // 0..7
    int ky = 2 * u;
    size_t in_idx = ((((size_t)lj * 64 + i) * 64 + o) * 144) + kx * Mk + ky;  // even
    float4 v = *(const float4*)(scw + 2 * in_idx);
    size_t o0 = ((((size_t)(lj * 12 + kx) * Mk + ky) * 64 + i) * 64 + o);
    size_t o1 = ((((size_t)(lj * 12 + kx) * Mk + ky + 1) * 64 + i) * 64 + o);
    *(float2*)(scwT + 2 * o0) = make_float2(v.x, v.y);
    *(float2*)(scwT + 2 * o1) = make_float2(v.z, v.w);
}

// ------- DFT along W of x (all 16 batches, 4096 rows), lane-per-row -------
__global__ __launch_bounds__(64) void k_dftw_x(const float* __restrict__ x,
                                               float* __restrict__ Xxw,
                                               const float* __restrict__ twc,
                                               const float* __restrict__ tws) {
    int r = blockIdx.x * 64 + threadIdx.x;  // 0..4095
    const float* hp = x + (size_t)r * Wn;
    float xr[Mk], xi[Mk];
#pragma unroll
    for (int k = 0; k < Mk; ++k) { xr[k] = 0.f; xi[k] = 0.f; }
    for (int w4 = 0; w4 < 64; ++w4) {
        float4 v = ((const float4*)hp)[w4];
        float vv[4] = {v.x, v.y, v.z, v.w};
#pragma unroll
        for (int j = 0; j < 4; ++j) {
            int wbase = (w4 * 4 + j) * Mk;  // wave-uniform -> scalar loads
#pragma unroll
            for (int k = 0; k < Mk; ++k) {
                xr[k] += vv[j] * twc[wbase + k];
                xi[k] -= vv[j] * tws[wbase + k];
            }
        }
    }
    float* op = Xxw + (size_t)r * (2 * Mk);
#pragma unroll
    for (int k = 0; k < Mk; ++k) { op[2 * k] = xr[k]; op[2 * k + 1] = xi[k]; }
}

// ------- DFT along H of x-modes -> Xfx[b][m][ky] (all batches) -------
__global__ __launch_bounds__(256) void k_xdfth(const float* __restrict__ Xxw,
                                               float* __restrict__ Xfx,
                                               const float* __restrict__ tc,
                                               const float* __restrict__ ts) {
    int t = blockIdx.x * 256 + threadIdx.x;  // < 4608
    if (t >= 16 * 288) return;
    int ky = t % Mk;
    int m  = (t / Mk) % NM;
    int b  = t / 288;
    int kx = (m < Mk) ? m : (232 + m);
    const float* base = Xxw + (size_t)b * Hn * 2 * Mk + 2 * ky;
    float ar = 0.f, ai = 0.f;
    for (int hh = 0; hh < Hn; ++hh) {
        float vr = base[hh * 2 * Mk];
        float vi = base[hh * 2 * Mk + 1];
        int idx = (kx * hh) & 255;
        float c = tc[idx], s = ts[idx];
        ar += vr * c + vi * s;   // * e^{-i theta}
        ai += vi * c - vr * s;
    }
    Xfx[2 * t] = ar;
    Xfx[2 * t + 1] = ai;
}

// ------- layer-0 mix: Z[b][ky][o][m] from Xfx (lift folded in) -------
__global__ __launch_bounds__(256, 2) void k_mix0(const float* __restrict__ Xfx,
                                                 const float* __restrict__ scwT,
                                                 const float* __restrict__ w0,
                                                 const float* __restrict__ b0v,
                                                 float* __restrict__ Z, int b0) {
    __shared__ float red[512];
    int blk = blockIdx.x;
    int b = blk / 288, mk = blk % 288;
    int m = mk / Mk, ky = mk % Mk;
    int t = threadIdx.x;
    int o = t & 63, q = t >> 6;
    float xr = Xfx[((b0 + b) * 288 + mk) * 2];
    float xi = Xfx[((b0 + b) * 288 + mk) * 2 + 1];
    int j = (m < Mk) ? 0 : 1;
    int kxw = (m < Mk) ? m : (m - Mk);
    const float* wb = scwT + ((size_t)((j * Mk + kxw) * Mk + ky) * 4096 + (q * 16) * 64 + o) * 2;
    float zr = 0.f, zi = 0.f;
#pragma unroll
    for (int ii = 0; ii < 16; ++ii) {
        int i = q * 16 + ii;
        float ar = w0[i] * xr, ai = w0[i] * xi;
        if (mk == 0) ar += 65536.0f * b0v[i];
        float wr = wb[ii * 128], wi = wb[ii * 128 + 1];
        zr += ar * wr - ai * wi;
        zi += ar * wi + ai * wr;
    }
    red[t * 2] = zr; red[t * 2 + 1] = zi;
    __syncthreads();
    if (t < 64) {
        float sr = red[t * 2] + red[(t + 64) * 2] + red[(t + 128) * 2] + red[(t + 192) * 2];
        float si = red[t * 2 + 1] + red[(t + 64) * 2 + 1] + red[(t + 128) * 2 + 1] + red[(t + 192) * 2 + 1];
        const float sc = 2.0f / 65536.0f;  // hermitian 2x + 1/(H*W)
        float2* zo = (float2*)Z + (((size_t)b * Mk + ky) * 64 + t) * 24 + m;
        *zo = make_float2(sr * sc, si * sc);
    }
}

// ------- H-DFT via MFMA: Xf[b][m][ky][i] from Xw[b][ky][hh][i][2] -------
// Per block (b,ky): C[48][128] = T(48x256 fp16) @ XwPlane(256x128 fp16/16)
// rows 0..23 = cos(kx m), rows 24..47 = sin; chan = 2i+p.
// Xf_r = (C[m][2i] + C[24+m][2i+1])*16 ; Xf_i = (C[m][2i+1] - C[24+m][2i])*16
__global__ __launch_bounds__(256) void k_dfth(const float* __restrict__ Xw,
                                              float* __restrict__ Xf2,
                                              const unsigned short* __restrict__ tfr) {
    __shared__ __align__(16) char smem[65536];
    int b = blockIdx.x / 12, ky = blockIdx.x % 12;
    int t = threadIdx.x;
    int lane = t & 63, q = t >> 6;
    // stage: Xw plane [256 hh][128 chan] fp32 -> LDS [128 chan][256 hh] fp16
    // (scaled 1/16; XOR-swizzled byte off ^ ((chan&7)<<4) within 512B rows)
    const float* P = Xw + ((size_t)b * 12 + ky) * 32768;
    int c = lane;  // chan pair (2c, 2c+1)
#pragma unroll 4
    for (int k = 0; k < 32; ++k) {
        int hh0 = k * 8 + q * 2;
        float2 a  = *(const float2*)(P + hh0 * 128 + 2 * c);
        float2 bv = *(const float2*)(P + (hh0 + 1) * 128 + 2 * c);
        unsigned int u0 = f2h(a.x * 0.0625f) | ((unsigned int)f2h(bv.x * 0.0625f) << 16);
        unsigned int u1 = f2h(a.y * 0.0625f) | ((unsigned int)f2h(bv.y * 0.0625f) << 16);
        int ch0 = 2 * c, ch1 = 2 * c + 1;
        *(unsigned int*)(smem + ch0 * 512 + ((2 * hh0) ^ ((ch0 & 7) << 4))) = u0;
        *(unsigned int*)(smem + ch1 * 512 + ((2 * hh0) ^ ((ch1 & 7) << 4))) = u1;
    }
    __syncthreads();
    // MFMA: wave q handles coltiles {2q, 2q+1}, all 3 M-tiles
    int ct0 = q * 2;
    int tg = (lane >> 4) & 3;
    f32x4 a00 = {0,0,0,0}, a01 = {0,0,0,0}, a10 = {0,0,0,0};
    f32x4 a11 = {0,0,0,0}, a20 = {0,0,0,0}, a21 = {0,0,0,0};
    const uint4* tf4 = (const uint4*)tfr;
#pragma unroll
    for (int s = 0; s < 8; ++s) {
        half8 af0 = __builtin_bit_cast(half8, tf4[(s * 3 + 0) * 64 + lane]);
        half8 af1 = __builtin_bit_cast(half8, tf4[(s * 3 + 1) * 64 + lane]);
        half8 af2 = __builtin_bit_cast(half8, tf4[(s * 3 + 2) * 64 + lane]);
        int chan0 = ct0 * 16 + (lane & 15);
        int chan1 = chan0 + 16;
        int off = s * 64 + tg * 16;
        half8 b0 = *(const half8*)(smem + chan0 * 512 + (off ^ ((chan0 & 7) << 4)));
        half8 b1 = *(const half8*)(smem + chan1 * 512 + (off ^ ((chan1 & 7) << 4)));
        a00 = __builtin_amdgcn_mfma_f32_16x16x32_f16(af0, b0, a00, 0, 0, 0);
        a01 = __builtin_amdgcn_mfma_f32_16x16x32_f16(af0, b1, a01, 0, 0, 0);
        a10 = __builtin_amdgcn_mfma_f32_16x16x32_f16(af1, b0, a10, 0, 0, 0);
        a11 = __builtin_amdgcn_mfma_f32_16x16x32_f16(af1, b1, a11, 0, 0, 0);
        a20 = __builtin_amdgcn_mfma_f32_16x16x32_f16(af2, b0, a20, 0, 0, 0);
        a21 = __builtin_amdgcn_mfma_f32_16x16x32_f16(af2, b1, a21, 0, 0, 0);
    }
    __syncthreads();   // staging dead; reuse LDS for C[48][128] f32 (24 KB)
    float* Cs = (float*)smem;
    {
        int rl = (lane >> 4) * 4;
        int chan0 = ct0 * 16 + (lane & 15);
#pragma unroll
        for (int r = 0; r < 4; ++r) {
            Cs[(0  + rl + r) * 128 + chan0]      = a00[r];
            Cs[(0  + rl + r) * 128 + chan0 + 16] = a01[r];
            Cs[(16 + rl + r) * 128 + chan0]      = a10[r];
            Cs[(16 + rl + r) * 128 + chan0 + 16] = a11[r];
            Cs[(32 + rl + r) * 128 + chan0]      = a20[r];
            Cs[(32 + rl + r) * 128 + chan0 + 16] = a21[r];
        }
    }
    __syncthreads();
#pragma unroll
    for (int k = 0; k < 6; ++k) {
        int p = t + 256 * k;      // p = m*64 + i
        int m = p >> 6, i = p & 63;
        float r1 = Cs[m * 128 + 2 * i];
        float i1 = Cs[m * 128 + 2 * i + 1];
        float r2 = Cs[(24 + m) * 128 + 2 * i];
        float i2 = Cs[(24 + m) * 128 + 2 * i + 1];
        ((float2*)Xf2)[((size_t)b * 288 + m * 12 + ky) * 64 + i] =
            make_float2((r1 + i2) * 16.0f, (i1 - r2) * 16.0f);
    }
}

// ------- mode mix (layers 1..3): Z[o] = sum_i W[i][o] * Xf[i] -------
__global__ __launch_bounds__(256, 2) void k_mixZ(const float* __restrict__ Xf2,
                                                 const float* __restrict__ scwT,
                                                 float* __restrict__ Z, int l) {
    __shared__ float red[512];
    __shared__ float xf[128];
    int blk = blockIdx.x;
    int b = blk / 288, mk = blk % 288;
    int m = mk / Mk, ky = mk % Mk;
    int t = threadIdx.x;
    if (t < 64) {
        float2 v = ((const float2*)Xf2)[((size_t)b * 288 + mk) * 64 + t];
        xf[2 * t] = v.x; xf[2 * t + 1] = v.y;
    }
    __syncthreads();
    int o = t & 63, q = t >> 6;
    int j = (m < Mk) ? 0 : 1;
    int kxw = (m < Mk) ? m : (m - Mk);
    const float* wb = scwT + ((size_t)(((l * 2 + j) * Mk + kxw) * Mk + ky) * 4096 + (q * 16) * 64 + o) * 2;
    float zr = 0.f, zi = 0.f;
#pragma unroll
    for (int ii = 0; ii < 16; ++ii) {
        float br = xf[(q * 16 + ii) * 2], bi = xf[(q * 16 + ii) * 2 + 1];
        float wr = wb[ii * 128], wi = wb[ii * 128 + 1];
        zr += br * wr - bi * wi;
        zi += br * wi + bi * wr;
    }
    red[t * 2] = zr; red[t * 2 + 1] = zi;
    __syncthreads();
    if (t < 64) {
        float sr = red[t * 2] + red[(t + 64) * 2] + red[(t + 128) * 2] + red[(t + 192) * 2];
        float si = red[t * 2 + 1] + red[(t + 64) * 2 + 1] + red[(t + 128) * 2 + 1] + red[(t + 192) * 2 + 1];
        const float sc = 2.0f / 65536.0f;
        float2* zo = (float2*)Z + (((size_t)b * Mk + ky) * 64 + t) * 24 + m;
        *zo = make_float2(sr * sc, si * sc);
    }
}

// ------- fused A: idft_h + idft_w + pointwise + gelu + dft_w(h_new, MFMA) -------
// xh/hn may alias (in-place, per-fiber, reads precede writes).
// LDS union (32 KiB): Ysh+csm alive through phase b; hsf fp16 [64][256]
// XOR-swizzled from staging (barrier-protected alias).
__global__ __launch_bounds__(256) void k_fusedA(const float* xh,
        const float* __restrict__ Zb, const float* __restrict__ pww,
        const float* __restrict__ pwb, const float* __restrict__ w0,
        const float* __restrict__ b0v, float* hn, float* __restrict__ XwOut,
        const float* __restrict__ tcs, const unsigned short* __restrict__ bfr,
        int l, int first) {
    __shared__ __align__(16) char smem[32768];
    float* Ysh = (float*)smem;
    float* csm = (float*)(smem + 6144);
    _Float16* hsf = (_Float16*)smem;
    int b  = blockIdx.x >> 8;
    int hh = blockIdx.x & 255;
    int w  = threadIdx.x;
    const float2* tc2 = (const float2*)tcs;
    if (w < NM) {
        int kx = (w < Mk) ? w : (232 + w);
        float2 cs = tc2[(kx * hh) & 255];
        csm[2 * w] = cs.x; csm[2 * w + 1] = cs.y;
    }
    __syncthreads();
    const float* Zbb = Zb + (size_t)b * 36864;
    const float4* cs4 = (const float4*)csm;
#pragma unroll
    for (int r3 = 0; r3 < 3; ++r3) {
        int p = w + 256 * r3;          // p = o*12 + ky
        int o = p / Mk, ky = p % Mk;
        const float4* zv = (const float4*)(Zbb + ((size_t)ky * 64 + o) * 48);
        float yr = 0.f, yi = 0.f;
#pragma unroll
        for (int mm = 0; mm < 12; ++mm) {   // two modes per float4
            float4 z  = zv[mm];
            float4 cc = cs4[mm];
            yr += z.x * cc.x - z.y * cc.y + z.z * cc.z - z.w * cc.w;
            yi += z.x * cc.y + z.y * cc.x + z.z * cc.w + z.w * cc.z;
        }
        Ysh[p * 2] = yr; Ysh[p * 2 + 1] = yi;
    }
    __syncthreads();
    float cwv[Mk], swv[Mk];
#pragma unroll
    for (int k = 0; k < Mk; ++k) {
        float2 cs = tc2[(k * w) & 255];
        cwv[k] = cs.x; swv[k] = cs.y;
    }
    float acc[Cn];
#pragma unroll
    for (int o = 0; o < Cn; ++o) {
        const float4* yv = (const float4*)(Ysh + o * 24);
        float4 q0 = yv[0];
        float a = pwb[l * Cn + o] + 0.5f * q0.x + q0.z * cwv[1] - q0.w * swv[1];
#pragma unroll
        for (int j = 1; j < 6; ++j) {
            float4 qj = yv[j];
            a += qj.x * cwv[2 * j] - qj.y * swv[2 * j]
               + qj.z * cwv[2 * j + 1] - qj.w * swv[2 * j + 1];
        }
        acc[o] = a;
    }
    __syncthreads();   // Ysh/csm reads done; hsf may overwrite after this
    const float* wwb = pww + l * Cn * Cn;
    if (first) {
        float xv = xh[(size_t)b * HW + hh * 256 + w];
#pragma unroll 1
        for (int ic = 0; ic < 4; ++ic) {
            float v[16];
#pragma unroll
            for (int j2 = 0; j2 < 16; ++j2)
                v[j2] = w0[ic * 16 + j2] * xv + b0v[ic * 16 + j2];
#pragma unroll
            for (int o = 0; o < Cn; ++o) {
                const float* wr = wwb + o * Cn + ic * 16;  // uniform -> s_load
                float a = acc[o];
#pragma unroll
                for (int j2 = 0; j2 < 16; ++j2) a += v[j2] * wr[j2];
                acc[o] = a;
            }
        }
    } else {
        const float* hb = xh + (size_t)b * Cn * HW + hh * 256 + w;
#pragma unroll 1
        for (int ic = 0; ic < 4; ++ic) {
            float v[16];
#pragma unroll
            for (int j2 = 0; j2 < 16; ++j2)
                v[j2] = hb[(size_t)(ic * 16 + j2) * HW];
#pragma unroll
            for (int o = 0; o < Cn; ++o) {
                const float* wr = wwb + o * Cn + ic * 16;
                float a = acc[o];
#pragma unroll
                for (int j2 = 0; j2 < 16; ++j2) a += v[j2] * wr[j2];
                acc[o] = a;
            }
        }
    }
    // gelu + store h (fp32) + stage fp16 into LDS (XOR-swizzled); acc dies here
    float* ob = hn + (size_t)b * Cn * HW + hh * 256 + w;
#pragma unroll
    for (int o = 0; o < Cn; ++o) {
        float g = gelu_exact(acc[o]);
        ob[(size_t)o * HW] = g;
        hsf[o * 256 + (((w >> 3) ^ (o & 7)) << 3) + (w & 7)] = (_Float16)g;
    }
    __syncthreads();
    // MFMA W-DFT: C[64 o2][32 cols] = hsf(64x256 fp16) @ Bfrag(256x32 fp16)
    // col = 2ky+p; only ky<12 stored (cols 24..31 computed but dead)
    {
        int lane = w & 63, q = w >> 6;
        int arow = q * 16 + (lane & 15);
        int tgrp = (lane >> 4) & 3;
        const uint4* bt = (const uint4*)bfr;
        f32x4 ac0 = {0.f, 0.f, 0.f, 0.f};
        f32x4 ac1 = {0.f, 0.f, 0.f, 0.f};
#pragma unroll
        for (int s = 0; s < 8; ++s) {
            int abyte = (arow * 512 + s * 64 + tgrp * 16) ^ ((arow & 7) << 4);
            half8 af = __builtin_bit_cast(half8, *(const uint4*)(smem + abyte));
            half8 b0 = __builtin_bit_cast(half8, bt[(s * 2 + 0) * 64 + lane]);
            half8 b1 = __builtin_bit_cast(half8, bt[(s * 2 + 1) * 64 + lane]);
            ac0 = __builtin_amdgcn_mfma_f32_16x16x32_f16(af, b0, ac0, 0, 0, 0);
            ac1 = __builtin_amdgcn_mfma_f32_16x16x32_f16(af, b1, ac1, 0, 0, 0);
        }
        // C layout: col = lane&15, row = (lane>>4)*4 + reg  (row = channel i)
        float* Xwb = XwOut + (size_t)b * 393216;
        int rbase = q * 16 + (lane >> 4) * 4;
#pragma unroll
        for (int n = 0; n < 2; ++n) {
            f32x4 ac = n ? ac1 : ac0;
            int col = n * 16 + (lane & 15);
            int ky = col >> 1, p = col & 1;
            if (ky < Mk) {
                float* dst = Xwb + (size_t)ky * 32768 + hh * 128 + rbase * 2 + p;
                dst[0] = ac[0]; dst[2] = ac[1]; dst[4] = ac[2]; dst[6] = ac[3];
            }
        }
    }
}

// ------- fused B (layer 3): idft + pointwise + fc1/gelu/fc2 (d-tiled) -------
__global__ __launch_bounds__(256) void k_fusedB(const float* __restrict__ h,
        const float* __restrict__ Zb, const float* __restrict__ pww,
        const float* __restrict__ pwb, const float* __restrict__ fc1w,
        const float* __restrict__ fc1b, const float* __restrict__ fc2w,
        const float* __restrict__ fc2b, float* __restrict__ outp,
        const float* __restrict__ tcs) {
    __shared__ __align__(16) float Ysh[1536];
    __shared__ __align__(16) float csm[48];
    int b  = blockIdx.x >> 8;
    int hh = blockIdx.x & 255;
    int w  = threadIdx.x;
    const float2* tc2 = (const float2*)tcs;
    if (w < NM) {
        int kx = (w < Mk) ? w : (232 + w);
        float2 cs = tc2[(kx * hh) & 255];
        csm[2 * w] = cs.x; csm[2 * w + 1] = cs.y;
    }
    __syncthreads();
    const float* Zbb = Zb + (size_t)b * 36864;
    const float4* cs4 = (const float4*)csm;
#pragma unroll
    for (int r3 = 0; r3 < 3; ++r3) {
        int p = w + 256 * r3;
        int o = p / Mk, ky = p % Mk;
        const float4* zv = (const float4*)(Zbb + ((size_t)ky * 64 + o) * 48);
        float yr = 0.f, yi = 0.f;
#pragma unroll
        for (int mm = 0; mm < 12; ++mm) {
            float4 z  = zv[mm];
            float4 cc = cs4[mm];
            yr += z.x * cc.x - z.y * cc.y + z.z * cc.z - z.w * cc.w;
            yi += z.x * cc.y + z.y * cc.x + z.z * cc.w + z.w * cc.z;
        }
        Ysh[p * 2] = yr; Ysh[p * 2 + 1] = yi;
    }
    __syncthreads();
    float cwv[Mk], swv[Mk];
#pragma unroll
    for (int k = 0; k < Mk; ++k) {
        float2 cs = tc2[(k * w) & 255];
        cwv[k] = cs.x; swv[k] = cs.y;
    }
    float acc[Cn];
#pragma unroll
    for (int o = 0; o < Cn; ++o) {
        const float4* yv = (const float4*)(Ysh + o * 24);
        float4 q0 = yv[0];
        float a = pwb[3 * Cn + o] + 0.5f * q0.x + q0.z * cwv[1] - q0.w * swv[1];
#pragma unroll
        for (int j = 1; j < 6; ++j) {
            float4 qj = yv[j];
            a += qj.x * cwv[2 * j] - qj.y * swv[2 * j]
               + qj.z * cwv[2 * j + 1] - qj.w * swv[2 * j + 1];
        }
        acc[o] = a;
    }
    const float* wwb = pww + 3 * Cn * Cn;
    const float* hb = h + (size_t)b * Cn * HW + hh * 256 + w;
#pragma unroll 1
    for (int ic = 0; ic < 4; ++ic) {
        float v[16];
#pragma unroll
        for (int j2 = 0; j2 < 16; ++j2)
            v[j2] = hb[(size_t)(ic * 16 + j2) * HW];
#pragma unroll
        for (int o = 0; o < Cn; ++o) {
            const float* wr = wwb + o * Cn + ic * 16;
            float a = acc[o];
#pragma unroll
            for (int j2 = 0; j2 < 16; ++j2) a += v[j2] * wr[j2];
            acc[o] = a;
        }
    }
    // fc1 -> gelu -> fc2, d tiled by 32: 32 independent accumulators (ILP)
    float outv = fc2b[0];
#pragma unroll 1
    for (int dt = 0; dt < 4; ++dt) {
        float hid[32];
#pragma unroll
        for (int j2 = 0; j2 < 32; ++j2) hid[j2] = fc1b[dt * 32 + j2];
#pragma unroll 8
        for (int o = 0; o < Cn; ++o) {
            float a = acc[o];
            const float* wr = fc1w + o * FCH + dt * 32;  // uniform -> s_load
#pragma unroll
            for (int j2 = 0; j2 < 32; ++j2) hid[j2] += a * wr[j2];
        }
#pragma unroll
        for (int j2 = 0; j2 < 32; ++j2)
            outv += gelu_exact(hid[j2]) * fc2w[dt * 32 + j2];
    }
    outp[(size_t)b * HW + hh * 256 + w] = outv;
}

extern "C" void kernel_launch(void* const* d_in, const int* in_sizes, int n_in,
                              void* d_out, int out_size, void* d_ws, size_t ws_size,
                              hipStream_t stream) {
    const float* x    = (const float*)d_in[0];
    const float* fc0w = (const float*)d_in[1];
    const float* fc0b = (const float*)d_in[2];
    const float* scw  = (const float*)d_in[3];
    const float* pww  = (const float*)d_in[4];
    const float* pwb  = (const float*)d_in[5];
    const float* fc1w = (const float*)d_in[6];
    const float* fc1b = (const float*)d_in[7];
    const float* fc2w = (const float*)d_in[8];
    const float* fc2b = (const float*)d_in[9];
    float* out = (float*)d_out;
    float* ws  = (float*)d_ws;

    // base: 256+256+3072+3072+512+4096+6144+9216+9437184 = 9,463,808 floats
    // per batch: h 4,194,304 + Xw 393,216 + Z 36,864 + Xf 36,864 = 4,661,248
    const size_t basef = 9463808;
    const size_t perbf = 4661248;
    int bc = 0;
    for (int cand = 16; cand >= 1; cand >>= 1)
        if ((basef + perbf * (size_t)cand) * 4 <= ws_size) { bc = cand; break; }
    if (bc == 0) return;  // diagnosable: zero output

    float* tabc = ws;
    float* tabs = tabc + 256;
    float* twc  = tabs + 256;
    float* tws_ = twc + 3072;
    float* tcs  = tws_ + 3072;          // float2[256]  -> 512 floats
    float* bfr  = tcs + 512;            // fp16[8192]  W-DFT B-frags -> 4096 floats
    float* tfr  = bfr + 4096;           // fp16[12288] H-DFT A-frags -> 6144 floats
    float* Xfx  = tfr + 6144;           // 9216
    float* scwT = Xfx + 9216;           // 9,437,184
    float* hbuf = ws + basef;           // bc*4,194,304 (also Xxw temp 98,304)
    float* Xw   = hbuf + (size_t)bc * 4194304;
    float* Zb   = Xw + (size_t)bc * 393216;
    float* Xf2  = Zb + (size_t)bc * 36864;

    k_init_tables<<<1, 256, 0, stream>>>(tabc, tabs, twc, tws_, tcs,
                                         (unsigned short*)bfr,
                                         (unsigned short*)tfr);
    k_prep_w<<<9216, 256, 0, stream>>>(scw, scwT);
    k_dftw_x<<<64, 64, 0, stream>>>(x, hbuf, twc, tws_);
    k_xdfth<<<18, 256, 0, stream>>>(hbuf, Xfx, tabc, tabs);

    for (int b0 = 0; b0 < 16; b0 += bc) {
        k_mix0<<<bc * 288, 256, 0, stream>>>(Xfx, scwT, fc0w, fc0b, Zb, b0);
        k_fusedA<<<bc * 256, 256, 0, stream>>>(x + (size_t)b0 * HW, Zb, pww, pwb,
                                               fc0w, fc0b, hbuf, Xw,
                                               tcs, (const unsigned short*)bfr, 0, 1);
        for (int l = 1; l <= 2; ++l) {
            k_dfth<<<bc * 12, 256, 0, stream>>>(Xw, Xf2, (const unsigned short*)tfr);
            k_mixZ<<<bc * 288, 256, 0, stream>>>(Xf2, scwT, Zb, l);
            k_fusedA<<<bc * 256, 256, 0, stream>>>(hbuf, Zb, pww, pwb,
                                                   fc0w, fc0b, hbuf, Xw,
                                                   tcs, (const unsigned short*)bfr, l, 0);
        }
        k_dfth<<<bc * 12, 256, 0, stream>>>(Xw, Xf2, (const unsigned short*)tfr);
        k_mixZ<<<bc * 288, 256, 0, stream>>>(Xf2, scwT, Zb, 3);
        k_fusedB<<<bc * 256, 256, 0, stream>>>(hbuf, Zb, pww, pwb, fc1w, fc1b,
                                               fc2w, fc2b, out + (size_t)b0 * HW,
                                               tcs);
    }
}

// Round 5
// 1327.079 us; speedup vs baseline: 3.6976x; 2.3214x over previous
//
#include <hip/hip_runtime.h>
#include <hip/hip_bf16.h>
#include <math.h>

#define Hn 256
#define Wn 256
#define Cn 64
#define Mk 12
#define NM 24
#define FCH 128
#define HW 65536

using half8 = __attribute__((ext_vector_type(8))) _Float16;
using f32x4 = __attribute__((ext_vector_type(4))) float;

__device__ __forceinline__ float gelu_exact(float x) {
    return 0.5f * x * (1.0f + erff(x * 0.7071067811865476f));
}
__device__ __forceinline__ unsigned short f2h(float f) {
    _Float16 h = (_Float16)f;
    return __builtin_bit_cast(unsigned short, h);
}

// ---------------- trig tables ----------------
// bfr: fusedA W-DFT B-frag fp16 [s8][n2][lane][j]: col=n*16+(l&15); ky=col>>1,
//      p=col&1; k=s*32+((l>>4)&3)*8+j; val = p ? -sin(ky k) : cos(ky k)
// tfr: k_dfth H-DFT A-frag fp16 [s8][mt3][lane][j]: row=mt*16+(l&15);
//      hh=s*32+((l>>4)&3)*8+j; row<24: cos(kx(row) hh) else sin(kx(row-24) hh)
__global__ __launch_bounds__(256) void k_init_tables(float* tc, float* ts,
                                                     float* twc, float* tws,
                                                     float* tcs,
                                                     unsigned short* bfr,
                                                     unsigned short* tfr) {
    int i = threadIdx.x;  // 0..255
    const float step = 0.024543692606170259f;  // 2*pi/256
    float c = cosf(i * step), s = sinf(i * step);
    tc[i] = c; ts[i] = s;
    tcs[2 * i] = c; tcs[2 * i + 1] = s;
    for (int k = 0; k < Mk; ++k) {
        int idx = (i * k) & 255;
        twc[i * Mk + k] = cosf(idx * step);
        tws[i * Mk + k] = sinf(idx * step);
    }
    for (int e = i; e < 8192; e += 256) {
        int j  = e & 7;
        int l  = (e >> 3) & 63;
        int sn = e >> 9;            // s*2+n
        int col = (sn & 1) * 16 + (l & 15);
        int ky = col >> 1, p = col & 1;
        int k  = (sn >> 1) * 32 + ((l >> 4) & 3) * 8 + j;
        int idx = (ky * k) & 255;
        float v = p ? -sinf(idx * step) : cosf(idx * step);
        bfr[e] = f2h(v);
    }
    for (int e = i; e < 12288; e += 256) {
        int j  = e & 7;
        int l  = (e >> 3) & 63;
        int sm = e >> 9;            // s*3+mt
        int mt = sm % 3, s2 = sm / 3;
        int r  = mt * 16 + (l & 15);
        int hh = s2 * 32 + ((l >> 4) & 3) * 8 + j;
        int m  = (r < 24) ? r : (r - 24);
        int kx = (m < Mk) ? m : (232 + m);
        int idx = (kx * hh) & 255;
        float v = (r < 24) ? cosf(idx * step) : sinf(idx * step);
        tfr[e] = f2h(v);
    }
}

// ---- weight/twiddle fragment tables for fusedA/fusedB MFMAs ----
// efr  [mt16][lane][j]: E[pix=mt*16+(l&15)][u=((l>>4)&3)*8+j]
//      u<12: cos(u pix), u<24: -sin((u-12) pix), else 0   (K padded to 32)
// pwfr [l4][ks2][nt4][lane][j]: pww[l][o=nt*16+(l&15)][i=ks*32+((l>>4)&3)*8+j]
// fc1fr[ks2][nt8][lane][j]: fc1w[i=ks*32+((l>>4)&3)*8+j][d=nt*16+(l&15)]
__global__ __launch_bounds__(256) void k_prep_frag(const float* __restrict__ pww,
                                                   const float* __restrict__ fc1w,
                                                   unsigned short* __restrict__ efr,
                                                   unsigned short* __restrict__ pwfr,
                                                   unsigned short* __restrict__ fc1fr) {
    int e = blockIdx.x * 256 + threadIdx.x;   // < 32768
    const float step = 0.024543692606170259f;
    int j = e & 7, l = (e >> 3) & 63;
    int row = l & 15;
    int k = ((l >> 4) & 3) * 8 + j;
    if (e < 8192) {
        int mt = (e >> 9) & 15;
        int pix = mt * 16 + row;
        float v = 0.f;
        if (k < 12) v = cosf(((k * pix) & 255) * step);
        else if (k < 24) v = -sinf((((k - 12) * pix) & 255) * step);
        efr[e] = f2h(v);
    } else if (e < 24576) {
        int e2 = e - 8192;
        int nt = (e2 >> 9) & 3;
        int ks = (e2 >> 11) & 1;
        int l4 = e2 >> 12;
        int o = nt * 16 + row;
        int i = ks * 32 + k;
        pwfr[e2] = f2h(pww[(size_t)(l4 * 64 + o) * 64 + i]);
    } else {
        int e2 = e - 24576;
        int nt = (e2 >> 9) & 7;
        int ks = (e2 >> 12) & 1;
        int d = nt * 16 + row;
        int i = ks * 32 + k;
        fc1fr[e2] = f2h(fc1w[i * 128 + d]);
    }
}

// ------- spectral weight transpose: scw[l,j,i,o,kx,ky,2] -> scwT[l,j,kx,ky,i,o,2]
__global__ __launch_bounds__(256) void k_prep_w(const float* __restrict__ scw,
                                                float* __restrict__ scwT) {
    int t = blockIdx.x * 256 + threadIdx.x;  // < 2,359,296
    int o  = t & 63;
    int i  = (t >> 6) & 63;
    int r  = t >> 12;           // lj*72 + kx*6 + u
    int u  = r % 6;
    int kx = (r / 6) % 12;
    int lj = r / 72;            // 0..7
    int ky = 2 * u;
    size_t in_idx = ((((size_t)lj * 64 + i) * 64 + o) * 144) + kx * Mk + ky;  // even
    float4 v = *(const float4*)(scw + 2 * in_idx);
    size_t o0 = ((((size_t)(lj * 12 + kx) * Mk + ky) * 64 + i) * 64 + o);
    size_t o1 = ((((size_t)(lj * 12 + kx) * Mk + ky + 1) * 64 + i) * 64 + o);
    *(float2*)(scwT + 2 * o0) = make_float2(v.x, v.y);
    *(float2*)(scwT + 2 * o1) = make_float2(v.z, v.w);
}

// ------- DFT along W of x (all 16 batches, 4096 rows), lane-per-row -------
__global__ __launch_bounds__(64) void k_dftw_x(const float* __restrict__ x,
                                               float* __restrict__ Xxw,
                                               const float* __restrict__ twc,
                                               const float* __restrict__ tws) {
    int r = blockIdx.x * 64 + threadIdx.x;  // 0..4095
    const float* hp = x + (size_t)r * Wn;
    float xr[Mk], xi[Mk];
#pragma unroll
    for (int k = 0; k < Mk; ++k) { xr[k] = 0.f; xi[k] = 0.f; }
    for (int w4 = 0; w4 < 64; ++w4) {
        float4 v = ((const float4*)hp)[w4];
        float vv[4] = {v.x, v.y, v.z, v.w};
#pragma unroll
        for (int j = 0; j < 4; ++j) {
            int wbase = (w4 * 4 + j) * Mk;
#pragma unroll
            for (int k = 0; k < Mk; ++k) {
                xr[k] += vv[j] * twc[wbase + k];
                xi[k] -= vv[j] * tws[wbase + k];
            }
        }
    }
    float* op = Xxw + (size_t)r * (2 * Mk);
#pragma unroll
    for (int k = 0; k < Mk; ++k) { op[2 * k] = xr[k]; op[2 * k + 1] = xi[k]; }
}

// ------- DFT along H of x-modes -> Xfx[b][m][ky] (all batches) -------
__global__ __launch_bounds__(256) void k_xdfth(const float* __restrict__ Xxw,
                                               float* __restrict__ Xfx,
                                               const float* __restrict__ tc,
                                               const float* __restrict__ ts) {
    int t = blockIdx.x * 256 + threadIdx.x;
    if (t >= 16 * 288) return;
    int ky = t % Mk;
    int m  = (t / Mk) % NM;
    int b  = t / 288;
    int kx = (m < Mk) ? m : (232 + m);
    const float* base = Xxw + (size_t)b * Hn * 2 * Mk + 2 * ky;
    float ar = 0.f, ai = 0.f;
    for (int hh = 0; hh < Hn; ++hh) {
        float vr = base[hh * 2 * Mk];
        float vi = base[hh * 2 * Mk + 1];
        int idx = (kx * hh) & 255;
        float c = tc[idx], s = ts[idx];
        ar += vr * c + vi * s;
        ai += vi * c - vr * s;
    }
    Xfx[2 * t] = ar;
    Xfx[2 * t + 1] = ai;
}

// ------- layer-0 mix: Z[b][ky][o][m] from Xfx (lift folded in) -------
__global__ __launch_bounds__(256, 2) void k_mix0(const float* __restrict__ Xfx,
                                                 const float* __restrict__ scwT,
                                                 const float* __restrict__ w0,
                                                 const float* __restrict__ b0v,
                                                 float* __restrict__ Z, int b0) {
    __shared__ float red[512];
    int blk = blockIdx.x;
    int b = blk / 288, mk = blk % 288;
    int m = mk / Mk, ky = mk % Mk;
    int t = threadIdx.x;
    int o = t & 63, q = t >> 6;
    float xr = Xfx[((b0 + b) * 288 + mk) * 2];
    float xi = Xfx[((b0 + b) * 288 + mk) * 2 + 1];
    int j = (m < Mk) ? 0 : 1;
    int kxw = (m < Mk) ? m : (m - Mk);
    const float* wb = scwT + ((size_t)((j * Mk + kxw) * Mk + ky) * 4096 + (q * 16) * 64 + o) * 2;
    float zr = 0.f, zi = 0.f;
#pragma unroll
    for (int ii = 0; ii < 16; ++ii) {
        int i = q * 16 + ii;
        float ar = w0[i] * xr, ai = w0[i] * xi;
        if (mk == 0) ar += 65536.0f * b0v[i];
        float wr = wb[ii * 128], wi = wb[ii * 128 + 1];
        zr += ar * wr - ai * wi;
        zi += ar * wi + ai * wr;
    }
    red[t * 2] = zr; red[t * 2 + 1] = zi;
    __syncthreads();
    if (t < 64) {
        float sr = red[t * 2] + red[(t + 64) * 2] + red[(t + 128) * 2] + red[(t + 192) * 2];
        float si = red[t * 2 + 1] + red[(t + 64) * 2 + 1] + red[(t + 128) * 2 + 1] + red[(t + 192) * 2 + 1];
        const float sc = 2.0f / 65536.0f;
        float2* zo = (float2*)Z + (((size_t)b * Mk + ky) * 64 + t) * 24 + m;
        *zo = make_float2(sr * sc, si * sc);
    }
}

// ------- H-DFT via MFMA: Xf[b][m][ky][i] from Xw[b][ky][hh][i][2] -------
__global__ __launch_bounds__(256) void k_dfth(const float* __restrict__ Xw,
                                              float* __restrict__ Xf2,
                                              const unsigned short* __restrict__ tfr) {
    __shared__ __align__(16) char smem[65536];
    int b = blockIdx.x / 12, ky = blockIdx.x % 12;
    int t = threadIdx.x;
    int lane = t & 63, q = t >> 6;
    const float* P = Xw + ((size_t)b * 12 + ky) * 32768;
    int c = lane;
#pragma unroll 4
    for (int k = 0; k < 32; ++k) {
        int hh0 = k * 8 + q * 2;
        float2 a  = *(const float2*)(P + hh0 * 128 + 2 * c);
        float2 bv = *(const float2*)(P + (hh0 + 1) * 128 + 2 * c);
        unsigned int u0 = f2h(a.x * 0.0625f) | ((unsigned int)f2h(bv.x * 0.0625f) << 16);
        unsigned int u1 = f2h(a.y * 0.0625f) | ((unsigned int)f2h(bv.y * 0.0625f) << 16);
        int ch0 = 2 * c, ch1 = 2 * c + 1;
        *(unsigned int*)(smem + ch0 * 512 + ((2 * hh0) ^ ((ch0 & 7) << 4))) = u0;
        *(unsigned int*)(smem + ch1 * 512 + ((2 * hh0) ^ ((ch1 & 7) << 4))) = u1;
    }
    __syncthreads();
    int ct0 = q * 2;
    int tg = (lane >> 4) & 3;
    f32x4 a00 = {0,0,0,0}, a01 = {0,0,0,0}, a10 = {0,0,0,0};
    f32x4 a11 = {0,0,0,0}, a20 = {0,0,0,0}, a21 = {0,0,0,0};
    const uint4* tf4 = (const uint4*)tfr;
#pragma unroll
    for (int s = 0; s < 8; ++s) {
        half8 af0 = __builtin_bit_cast(half8, tf4[(s * 3 + 0) * 64 + lane]);
        half8 af1 = __builtin_bit_cast(half8, tf4[(s * 3 + 1) * 64 + lane]);
        half8 af2 = __builtin_bit_cast(half8, tf4[(s * 3 + 2) * 64 + lane]);
        int chan0 = ct0 * 16 + (lane & 15);
        int chan1 = chan0 + 16;
        int off = s * 64 + tg * 16;
        half8 b0 = *(const half8*)(smem + chan0 * 512 + (off ^ ((chan0 & 7) << 4)));
        half8 b1 = *(const half8*)(smem + chan1 * 512 + (off ^ ((chan1 & 7) << 4)));
        a00 = __builtin_amdgcn_mfma_f32_16x16x32_f16(af0, b0, a00, 0, 0, 0);
        a01 = __builtin_amdgcn_mfma_f32_16x16x32_f16(af0, b1, a01, 0, 0, 0);
        a10 = __builtin_amdgcn_mfma_f32_16x16x32_f16(af1, b0, a10, 0, 0, 0);
        a11 = __builtin_amdgcn_mfma_f32_16x16x32_f16(af1, b1, a11, 0, 0, 0);
        a20 = __builtin_amdgcn_mfma_f32_16x16x32_f16(af2, b0, a20, 0, 0, 0);
        a21 = __builtin_amdgcn_mfma_f32_16x16x32_f16(af2, b1, a21, 0, 0, 0);
    }
    __syncthreads();
    float* Cs = (float*)smem;
    {
        int rl = (lane >> 4) * 4;
        int chan0 = ct0 * 16 + (lane & 15);
#pragma unroll
        for (int r = 0; r < 4; ++r) {
            Cs[(0  + rl + r) * 128 + chan0]      = a00[r];
            Cs[(0  + rl + r) * 128 + chan0 + 16] = a01[r];
            Cs[(16 + rl + r) * 128 + chan0]      = a10[r];
            Cs[(16 + rl + r) * 128 + chan0 + 16] = a11[r];
            Cs[(32 + rl + r) * 128 + chan0]      = a20[r];
            Cs[(32 + rl + r) * 128 + chan0 + 16] = a21[r];
        }
    }
    __syncthreads();
#pragma unroll
    for (int k = 0; k < 6; ++k) {
        int p = t + 256 * k;
        int m = p >> 6, i = p & 63;
        float r1 = Cs[m * 128 + 2 * i];
        float i1 = Cs[m * 128 + 2 * i + 1];
        float r2 = Cs[(24 + m) * 128 + 2 * i];
        float i2 = Cs[(24 + m) * 128 + 2 * i + 1];
        ((float2*)Xf2)[((size_t)b * 288 + m * 12 + ky) * 64 + i] =
            make_float2((r1 + i2) * 16.0f, (i1 - r2) * 16.0f);
    }
}

// ------- mode mix (layers 1..3) -------
__global__ __launch_bounds__(256, 2) void k_mixZ(const float* __restrict__ Xf2,
                                                 const float* __restrict__ scwT,
                                                 float* __restrict__ Z, int l) {
    __shared__ float red[512];
    __shared__ float xf[128];
    int blk = blockIdx.x;
    int b = blk / 288, mk = blk % 288;
    int m = mk / Mk, ky = mk % Mk;
    int t = threadIdx.x;
    if (t < 64) {
        float2 v = ((const float2*)Xf2)[((size_t)b * 288 + mk) * 64 + t];
        xf[2 * t] = v.x; xf[2 * t + 1] = v.y;
    }
    __syncthreads();
    int o = t & 63, q = t >> 6;
    int j = (m < Mk) ? 0 : 1;
    int kxw = (m < Mk) ? m : (m - Mk);
    const float* wb = scwT + ((size_t)(((l * 2 + j) * Mk + kxw) * Mk + ky) * 4096 + (q * 16) * 64 + o) * 2;
    float zr = 0.f, zi = 0.f;
#pragma unroll
    for (int ii = 0; ii < 16; ++ii) {
        float br = xf[(q * 16 + ii) * 2], bi = xf[(q * 16 + ii) * 2 + 1];
        float wr = wb[ii * 128], wi = wb[ii * 128 + 1];
        zr += br * wr - bi * wi;
        zi += br * wi + bi * wr;
    }
    __syncthreads();
    red[t * 2] = zr; red[t * 2 + 1] = zi;
    __syncthreads();
    if (t < 64) {
        float sr = red[t * 2] + red[(t + 64) * 2] + red[(t + 128) * 2] + red[(t + 192) * 2];
        float si = red[t * 2 + 1] + red[(t + 64) * 2 + 1] + red[(t + 128) * 2 + 1] + red[(t + 192) * 2 + 1];
        const float sc = 2.0f / 65536.0f;
        float2* zo = (float2*)Z + (((size_t)b * Mk + ky) * 64 + t) * 24 + m;
        *zo = make_float2(sr * sc, si * sc);
    }
}

// ------- fused A: all-MFMA layer kernel -------
// LDS: [0,32K) A_lds[pix][chan] fp16 swz  (overlays Ysh [0,6K) then hsf [0,32K))
//      [32K,36K) Yfr B-frags; [36K,+192) csm. 6 barriers.
__global__ __launch_bounds__(256) void k_fusedA(const float* xh,
        const float* __restrict__ Zb, const float* __restrict__ pwb,
        const float* __restrict__ w0, const float* __restrict__ b0v,
        float* hn, float* __restrict__ XwOut,
        const float* __restrict__ tcs,
        const unsigned short* __restrict__ bfr,
        const unsigned short* __restrict__ efr,
        const unsigned short* __restrict__ pwfr,
        int l, int first) {
    __shared__ __align__(16) char smem[37120];
    float* Ysh = (float*)smem;
    char*  Yfr = smem + 32768;
    float* csm = (float*)(smem + 36864);
    int b  = blockIdx.x >> 8;
    int hh = blockIdx.x & 255;
    int w  = threadIdx.x;
    int lane = w & 63, q = w >> 6;
    int tg = (lane >> 4) & 3;
    const float2* tc2 = (const float2*)tcs;
    if (w < NM) {
        int kx = (w < Mk) ? w : (232 + w);
        float2 cs = tc2[(kx * hh) & 255];
        csm[2 * w] = cs.x; csm[2 * w + 1] = cs.y;
    }
    __syncthreads();
    // phase a: idft_h of Z -> Ysh[o][ky] complex
    const float* Zbb = Zb + (size_t)b * 36864;
    const float4* cs4 = (const float4*)csm;
#pragma unroll
    for (int r3 = 0; r3 < 3; ++r3) {
        int p = w + 256 * r3;
        int o = p / Mk, ky = p % Mk;
        const float4* zv = (const float4*)(Zbb + ((size_t)ky * 64 + o) * 48);
        float yr = 0.f, yi = 0.f;
#pragma unroll
        for (int mm = 0; mm < 12; ++mm) {
            float4 z  = zv[mm];
            float4 cc = cs4[mm];
            yr += z.x * cc.x - z.y * cc.y + z.z * cc.z - z.w * cc.w;
            yi += z.x * cc.y + z.y * cc.x + z.z * cc.w + z.w * cc.z;
        }
        Ysh[p * 2] = yr; Ysh[p * 2 + 1] = yi;
    }
    __syncthreads();
    // Y-stage: Yfr[nt=q][lane][j] fp16: Y[u][o], u=tg*8+j (u=0 halved), o=nt*16+(l&15)
    {
        int o = q * 16 + (lane & 15);
        unsigned pv[4];
#pragma unroll
        for (int jp = 0; jp < 4; ++jp) {
            unsigned short h2[2];
#pragma unroll
            for (int hzz = 0; hzz < 2; ++hzz) {
                int u = tg * 8 + jp * 2 + hzz;
                float v;
                if (u == 0) v = 0.5f * Ysh[o * 24];
                else if (u < 12) v = Ysh[o * 24 + 2 * u];
                else if (u < 24) v = Ysh[o * 24 + 2 * (u - 12) + 1];
                else v = 0.f;
                h2[hzz] = f2h(v);
            }
            pv[jp] = h2[0] | ((unsigned)h2[1] << 16);
        }
        uint4 pk = {pv[0], pv[1], pv[2], pv[3]};
        *(uint4*)(Yfr + (q * 64 + lane) * 16) = pk;
    }
    __syncthreads();
    // A-stage: h_old (or lift of x) -> A_lds[pix=w][i] fp16, XOR-swizzled
    {
        int swz = (w & 7) << 4;
        if (first) {
            float xv = xh[(size_t)b * HW + hh * 256 + w];
#pragma unroll
            for (int ic = 0; ic < 4; ++ic) {
                unsigned pv[8];
#pragma unroll
                for (int j2 = 0; j2 < 16; j2 += 2) {
                    float a0 = w0[ic * 16 + j2] * xv + b0v[ic * 16 + j2];
                    float a1 = w0[ic * 16 + j2 + 1] * xv + b0v[ic * 16 + j2 + 1];
                    pv[j2 >> 1] = f2h(a0) | ((unsigned)f2h(a1) << 16);
                }
                uint4 lo = {pv[0], pv[1], pv[2], pv[3]};
                uint4 hi = {pv[4], pv[5], pv[6], pv[7]};
                *(uint4*)(smem + ((w * 128 + ic * 32) ^ swz)) = lo;
                *(uint4*)(smem + ((w * 128 + ic * 32 + 16) ^ swz)) = hi;
            }
        } else {
            const float* hb = xh + (size_t)b * Cn * HW + hh * 256 + w;
#pragma unroll
            for (int ic = 0; ic < 4; ++ic) {
                unsigned pv[8];
#pragma unroll
                for (int j2 = 0; j2 < 16; j2 += 2) {
                    float a0 = hb[(size_t)(ic * 16 + j2) * HW];
                    float a1 = hb[(size_t)(ic * 16 + j2 + 1) * HW];
                    pv[j2 >> 1] = f2h(a0) | ((unsigned)f2h(a1) << 16);
                }
                uint4 lo = {pv[0], pv[1], pv[2], pv[3]};
                uint4 hi = {pv[4], pv[5], pv[6], pv[7]};
                *(uint4*)(smem + ((w * 128 + ic * 32) ^ swz)) = lo;
                *(uint4*)(smem + ((w * 128 + ic * 32 + 16) ^ swz)) = hi;
            }
        }
    }
    __syncthreads();
    // MFMA: C[pix][o] = E@Y + A_lds@pwfr ; +bias, gelu -> g[][][]
    float g[4][4][4];
    {
        const uint4* efr4 = (const uint4*)efr;
        const uint4* pw4  = (const uint4*)pwfr;
        float biasn[4];
        half8 ybf[4]; uint4 cwa[4], cwb[4];
#pragma unroll
        for (int nt = 0; nt < 4; ++nt) {
            biasn[nt] = pwb[l * 64 + nt * 16 + (lane & 15)];
            ybf[nt] = *(const half8*)(Yfr + (nt * 64 + lane) * 16);
            cwa[nt] = pw4[((l * 2 + 0) * 4 + nt) * 64 + lane];
            cwb[nt] = pw4[((l * 2 + 1) * 4 + nt) * 64 + lane];
        }
#pragma unroll
        for (int mt = 0; mt < 4; ++mt) {
            int mtA = q * 4 + mt;
            half8 ea = __builtin_bit_cast(half8, efr4[mtA * 64 + lane]);
            int row = mtA * 16 + (lane & 15);
            int rsw = (row & 7) << 4;
            half8 a0 = *(const half8*)(smem + ((row * 128 + tg * 16) ^ rsw));
            half8 a1 = *(const half8*)(smem + ((row * 128 + 64 + tg * 16) ^ rsw));
#pragma unroll
            for (int nt = 0; nt < 4; ++nt) {
                f32x4 acc = {0.f, 0.f, 0.f, 0.f};
                acc = __builtin_amdgcn_mfma_f32_16x16x32_f16(ea, ybf[nt], acc, 0, 0, 0);
                acc = __builtin_amdgcn_mfma_f32_16x16x32_f16(a0, __builtin_bit_cast(half8, cwa[nt]), acc, 0, 0, 0);
                acc = __builtin_amdgcn_mfma_f32_16x16x32_f16(a1, __builtin_bit_cast(half8, cwb[nt]), acc, 0, 0, 0);
#pragma unroll
                for (int r = 0; r < 4; ++r)
                    g[mt][nt][r] = gelu_exact(acc[r] + biasn[nt]);
            }
        }
    }
    // global h stores (float4 per tile)
    float* hnb = hn + (size_t)b * Cn * HW + hh * 256;
#pragma unroll
    for (int mt = 0; mt < 4; ++mt) {
        int pbase = (q * 4 + mt) * 16 + (lane >> 4) * 4;
#pragma unroll
        for (int nt = 0; nt < 4; ++nt) {
            int o = nt * 16 + (lane & 15);
            float4 hv = {g[mt][nt][0], g[mt][nt][1], g[mt][nt][2], g[mt][nt][3]};
            *(float4*)(hnb + (size_t)o * HW + pbase) = hv;
        }
    }
    __syncthreads();   // all A_lds reads done; hsf overlay begins
    // hsf stage: [o][pix swz] fp16, 8-B writes
#pragma unroll
    for (int mt = 0; mt < 4; ++mt) {
        int pbase = (q * 4 + mt) * 16 + (lane >> 4) * 4;
#pragma unroll
        for (int nt = 0; nt < 4; ++nt) {
            int o = nt * 16 + (lane & 15);
            int sidx = (((pbase >> 3) ^ (o & 7)) << 3) | (pbase & 7);
            uint2 pk2;
            pk2.x = f2h(g[mt][nt][0]) | ((unsigned)f2h(g[mt][nt][1]) << 16);
            pk2.y = f2h(g[mt][nt][2]) | ((unsigned)f2h(g[mt][nt][3]) << 16);
            *(uint2*)(smem + o * 512 + sidx * 2) = pk2;
        }
    }
    __syncthreads();
    // MFMA W-DFT: C[64 o2][32 cols] = hsf(64x256) @ Bfrag ; only ky<12 stored
    {
        int arow = q * 16 + (lane & 15);
        const uint4* bt = (const uint4*)bfr;
        f32x4 ac0 = {0.f, 0.f, 0.f, 0.f};
        f32x4 ac1 = {0.f, 0.f, 0.f, 0.f};
#pragma unroll
        for (int s = 0; s < 8; ++s) {
            int abyte = (arow * 512 + s * 64 + tg * 16) ^ ((arow & 7) << 4);
            half8 af = __builtin_bit_cast(half8, *(const uint4*)(smem + abyte));
            half8 b0 = __builtin_bit_cast(half8, bt[(s * 2 + 0) * 64 + lane]);
            half8 b1 = __builtin_bit_cast(half8, bt[(s * 2 + 1) * 64 + lane]);
            ac0 = __builtin_amdgcn_mfma_f32_16x16x32_f16(af, b0, ac0, 0, 0, 0);
            ac1 = __builtin_amdgcn_mfma_f32_16x16x32_f16(af, b1, ac1, 0, 0, 0);
        }
        float* Xwb = XwOut + (size_t)b * 393216;
        int rbase = q * 16 + (lane >> 4) * 4;
#pragma unroll
        for (int n = 0; n < 2; ++n) {
            f32x4 ac = n ? ac1 : ac0;
            int col = n * 16 + (lane & 15);
            int ky = col >> 1, p = col & 1;
            if (ky < Mk) {
                float* dst = Xwb + (size_t)ky * 32768 + hh * 128 + rbase * 2 + p;
                dst[0] = ac[0]; dst[2] = ac[1]; dst[4] = ac[2]; dst[6] = ac[3];
            }
        }
    }
}

// ------- fused B (layer 3): all-MFMA idft+conv+fc1/gelu/fc2 -------
__global__ __launch_bounds__(256) void k_fusedB(const float* __restrict__ h,
        const float* __restrict__ Zb, const float* __restrict__ pwb,
        const float* __restrict__ fc1b, const float* __restrict__ fc2w,
        const float* __restrict__ fc2b, float* __restrict__ outp,
        const float* __restrict__ tcs,
        const unsigned short* __restrict__ efr,
        const unsigned short* __restrict__ pwfr,
        const unsigned short* __restrict__ fc1fr) {
    __shared__ __align__(16) char smem[37120];
    float* Ysh = (float*)smem;
    char*  Yfr = smem + 32768;
    float* csm = (float*)(smem + 36864);
    int b  = blockIdx.x >> 8;
    int hh = blockIdx.x & 255;
    int w  = threadIdx.x;
    int lane = w & 63, q = w >> 6;
    int tg = (lane >> 4) & 3;
    const float2* tc2 = (const float2*)tcs;
    if (w < NM) {
        int kx = (w < Mk) ? w : (232 + w);
        float2 cs = tc2[(kx * hh) & 255];
        csm[2 * w] = cs.x; csm[2 * w + 1] = cs.y;
    }
    __syncthreads();
    const float* Zbb = Zb + (size_t)b * 36864;
    const float4* cs4 = (const float4*)csm;
#pragma unroll
    for (int r3 = 0; r3 < 3; ++r3) {
        int p = w + 256 * r3;
        int o = p / Mk, ky = p % Mk;
        const float4* zv = (const float4*)(Zbb + ((size_t)ky * 64 + o) * 48);
        float yr = 0.f, yi = 0.f;
#pragma unroll
        for (int mm = 0; mm < 12; ++mm) {
            float4 z  = zv[mm];
            float4 cc = cs4[mm];
            yr += z.x * cc.x - z.y * cc.y + z.z * cc.z - z.w * cc.w;
            yi += z.x * cc.y + z.y * cc.x + z.z * cc.w + z.w * cc.z;
        }
        Ysh[p * 2] = yr; Ysh[p * 2 + 1] = yi;
    }
    __syncthreads();
    {
        int o = q * 16 + (lane & 15);
        unsigned pv[4];
#pragma unroll
        for (int jp = 0; jp < 4; ++jp) {
            unsigned short h2[2];
#pragma unroll
            for (int hzz = 0; hzz < 2; ++hzz) {
                int u = tg * 8 + jp * 2 + hzz;
                float v;
                if (u == 0) v = 0.5f * Ysh[o * 24];
                else if (u < 12) v = Ysh[o * 24 + 2 * u];
                else if (u < 24) v = Ysh[o * 24 + 2 * (u - 12) + 1];
                else v = 0.f;
                h2[hzz] = f2h(v);
            }
            pv[jp] = h2[0] | ((unsigned)h2[1] << 16);
        }
        uint4 pk = {pv[0], pv[1], pv[2], pv[3]};
        *(uint4*)(Yfr + (q * 64 + lane) * 16) = pk;
    }
    __syncthreads();
    {
        int swz = (w & 7) << 4;
        const float* hb = h + (size_t)b * Cn * HW + hh * 256 + w;
#pragma unroll
        for (int ic = 0; ic < 4; ++ic) {
            unsigned pv[8];
#pragma unroll
            for (int j2 = 0; j2 < 16; j2 += 2) {
                float a0 = hb[(size_t)(ic * 16 + j2) * HW];
                float a1 = hb[(size_t)(ic * 16 + j2 + 1) * HW];
                pv[j2 >> 1] = f2h(a0) | ((unsigned)f2h(a1) << 16);
            }
            uint4 lo = {pv[0], pv[1], pv[2], pv[3]};
            uint4 hi = {pv[4], pv[5], pv[6], pv[7]};
            *(uint4*)(smem + ((w * 128 + ic * 32) ^ swz)) = lo;
            *(uint4*)(smem + ((w * 128 + ic * 32 + 16) ^ swz)) = hi;
        }
    }
    __syncthreads();
    // conv+spec MFMA, M=o: wave q owns o-tile q; R[nt][r] = x1+x2+bias
    float R[16][4];
    {
        const uint4* efr4 = (const uint4*)efr;
        const uint4* pw4 = (const uint4*)pwfr;
        half8 ay  = *(const half8*)(Yfr + (q * 64 + lane) * 16);
        half8 aw0 = __builtin_bit_cast(half8, pw4[((3 * 2 + 0) * 4 + q) * 64 + lane]);
        half8 aw1 = __builtin_bit_cast(half8, pw4[((3 * 2 + 1) * 4 + q) * 64 + lane]);
        int obase = q * 16 + (lane >> 4) * 4;
        float4 bias4 = *(const float4*)(pwb + 3 * 64 + obase);
#pragma unroll
        for (int nt = 0; nt < 16; ++nt) {
            half8 eb = __builtin_bit_cast(half8, efr4[nt * 64 + lane]);
            int pix = nt * 16 + (lane & 15);
            int psw = (pix & 7) << 4;
            half8 b0 = *(const half8*)(smem + ((pix * 128 + tg * 16) ^ psw));
            half8 b1 = *(const half8*)(smem + ((pix * 128 + 64 + tg * 16) ^ psw));
            f32x4 acc = {0.f, 0.f, 0.f, 0.f};
            acc = __builtin_amdgcn_mfma_f32_16x16x32_f16(ay, eb, acc, 0, 0, 0);
            acc = __builtin_amdgcn_mfma_f32_16x16x32_f16(aw0, b0, acc, 0, 0, 0);
            acc = __builtin_amdgcn_mfma_f32_16x16x32_f16(aw1, b1, acc, 0, 0, 0);
            R[nt][0] = acc[0] + bias4.x; R[nt][1] = acc[1] + bias4.y;
            R[nt][2] = acc[2] + bias4.z; R[nt][3] = acc[3] + bias4.w;
        }
    }
    __syncthreads();
    // R^T -> A_lds[pix][chan] fp16 (8-B contiguous writes)
    {
        int obase = q * 16 + (lane >> 4) * 4;
#pragma unroll
        for (int nt = 0; nt < 16; ++nt) {
            int pix = nt * 16 + (lane & 15);
            uint2 pk2;
            pk2.x = f2h(R[nt][0]) | ((unsigned)f2h(R[nt][1]) << 16);
            pk2.y = f2h(R[nt][2]) | ((unsigned)f2h(R[nt][3]) << 16);
            *(uint2*)(smem + ((pix * 128 + obase * 2) ^ ((pix & 7) << 4))) = pk2;
        }
    }
    __syncthreads();
    // fc1 MFMA (M=pix) + gelu + fc2 reduce
    const uint4* f14 = (const uint4*)fc1fr;
    float w2v[8], fb1[8];
#pragma unroll
    for (int nt = 0; nt < 8; ++nt) {
        w2v[nt] = fc2w[nt * 16 + (lane & 15)];
        fb1[nt] = fc1b[nt * 16 + (lane & 15)];
    }
    float fb = fc2b[0];
    float* ob = outp + (size_t)b * HW + hh * 256;
#pragma unroll
    for (int mt = 0; mt < 4; ++mt) {
        int mtA = q * 4 + mt;
        int row = mtA * 16 + (lane & 15);
        int rsw = (row & 7) << 4;
        half8 a0 = *(const half8*)(smem + ((row * 128 + tg * 16) ^ rsw));
        half8 a1 = *(const half8*)(smem + ((row * 128 + 64 + tg * 16) ^ rsw));
        float s0 = 0.f, s1 = 0.f, s2 = 0.f, s3 = 0.f;
#pragma unroll
        for (int nt = 0; nt < 8; ++nt) {
            f32x4 acc = {0.f, 0.f, 0.f, 0.f};
            acc = __builtin_amdgcn_mfma_f32_16x16x32_f16(a0, __builtin_bit_cast(half8, f14[(0 * 8 + nt) * 64 + lane]), acc, 0, 0, 0);
            acc = __builtin_amdgcn_mfma_f32_16x16x32_f16(a1, __builtin_bit_cast(half8, f14[(1 * 8 + nt) * 64 + lane]), acc, 0, 0, 0);
            s0 += gelu_exact(acc[0] + fb1[nt]) * w2v[nt];
            s1 += gelu_exact(acc[1] + fb1[nt]) * w2v[nt];
            s2 += gelu_exact(acc[2] + fb1[nt]) * w2v[nt];
            s3 += gelu_exact(acc[3] + fb1[nt]) * w2v[nt];
        }
#pragma unroll
        for (int msk = 1; msk <= 8; msk <<= 1) {
            s0 += __shfl_xor(s0, msk);
            s1 += __shfl_xor(s1, msk);
            s2 += __shfl_xor(s2, msk);
            s3 += __shfl_xor(s3, msk);
        }
        int cc = lane & 15;
        if (cc < 4) {
            float v = (cc == 0) ? s0 : (cc == 1) ? s1 : (cc == 2) ? s2 : s3;
            ob[mtA * 16 + (lane >> 4) * 4 + cc] = v + fb;
        }
    }
}

extern "C" void kernel_launch(void* const* d_in, const int* in_sizes, int n_in,
                              void* d_out, int out_size, void* d_ws, size_t ws_size,
                              hipStream_t stream) {
    const float* x    = (const float*)d_in[0];
    const float* fc0w = (const float*)d_in[1];
    const float* fc0b = (const float*)d_in[2];
    const float* scw  = (const float*)d_in[3];
    const float* pww  = (const float*)d_in[4];
    const float* pwb  = (const float*)d_in[5];
    const float* fc1w = (const float*)d_in[6];
    const float* fc1b = (const float*)d_in[7];
    const float* fc2w = (const float*)d_in[8];
    const float* fc2b = (const float*)d_in[9];
    float* out = (float*)d_out;
    float* ws  = (float*)d_ws;

    // base floats: 7168 trig + 4096 bfr + 6144 tfr + 4096 efr + 8192 pwfr
    //            + 4096 fc1fr + 9216 Xfx + 9437184 scwT = 9,480,192
    const size_t basef = 9480192;
    const size_t perbf = 4661248;
    int bc = 0;
    for (int cand = 16; cand >= 1; cand >>= 1)
        if ((basef + perbf * (size_t)cand) * 4 <= ws_size) { bc = cand; break; }
    if (bc == 0) return;

    float* tabc = ws;
    float* tabs = tabc + 256;
    float* twc  = tabs + 256;
    float* tws_ = twc + 3072;
    float* tcs  = tws_ + 3072;
    float* bfr  = tcs + 512;            // fp16[8192]
    float* tfr  = bfr + 4096;           // fp16[12288]
    float* efr  = tfr + 6144;           // fp16[8192]
    float* pwfr = efr + 4096;           // fp16[16384]
    float* fc1f = pwfr + 8192;          // fp16[8192]
    float* Xfx  = fc1f + 4096;          // 9216
    float* scwT = Xfx + 9216;           // 9,437,184
    float* hbuf = ws + basef;
    float* Xw   = hbuf + (size_t)bc * 4194304;
    float* Zb   = Xw + (size_t)bc * 393216;
    float* Xf2  = Zb + (size_t)bc * 36864;

    k_init_tables<<<1, 256, 0, stream>>>(tabc, tabs, twc, tws_, tcs,
                                         (unsigned short*)bfr,
                                         (unsigned short*)tfr);
    k_prep_frag<<<128, 256, 0, stream>>>(pww, fc1w,
                                         (unsigned short*)efr,
                                         (unsigned short*)pwfr,
                                         (unsigned short*)fc1f);
    k_prep_w<<<9216, 256, 0, stream>>>(scw, scwT);
    k_dftw_x<<<64, 64, 0, stream>>>(x, hbuf, twc, tws_);
    k_xdfth<<<18, 256, 0, stream>>>(hbuf, Xfx, tabc, tabs);

    for (int b0 = 0; b0 < 16; b0 += bc) {
        k_mix0<<<bc * 288, 256, 0, stream>>>(Xfx, scwT, fc0w, fc0b, Zb, b0);
        k_fusedA<<<bc * 256, 256, 0, stream>>>(x + (size_t)b0 * HW, Zb, pwb,
                                               fc0w, fc0b, hbuf, Xw, tcs,
                                               (const unsigned short*)bfr,
                                               (const unsigned short*)efr,
                                               (const unsigned short*)pwfr, 0, 1);
        for (int l = 1; l <= 2; ++l) {
            k_dfth<<<bc * 12, 256, 0, stream>>>(Xw, Xf2, (const unsigned short*)tfr);
            k_mixZ<<<bc * 288, 256, 0, stream>>>(Xf2, scwT, Zb, l);
            k_fusedA<<<bc * 256, 256, 0, stream>>>(hbuf, Zb, pwb,
                                                   fc0w, fc0b, hbuf, Xw, tcs,
                                                   (const unsigned short*)bfr,
                                                   (const unsigned short*)efr,
                                                   (const unsigned short*)pwfr, l, 0);
        }
        k_dfth<<<bc * 12, 256, 0, stream>>>(Xw, Xf2, (const unsigned short*)tfr);
        k_mixZ<<<bc * 288, 256, 0, stream>>>(Xf2, scwT, Zb, 3);
        k_fusedB<<<bc * 256, 256, 0, stream>>>(hbuf, Zb, pwb, fc1b, fc2w, fc2b,
                                               out + (size_t)b0 * HW, tcs,
                                               (const unsigned short*)efr,
                                               (const unsigned short*)pwfr,
                                               (const unsigned short*)fc1f);
    }
}